// Round 8
// baseline (695.337 us; speedup 1.0000x reference)
//
#include <hip/hip_runtime.h>
#include <cstddef>

#define NRELS 8
#define EMB 128
#define HID 128
#define OUTD 256
#define HEADS 4
#define RANK 8
#define D2 512            // HEADS*HID, conv2 input dim
#define NEG_SLOPE 0.2f
#define LN_EPS 1e-5f

typedef short bf16x8 __attribute__((ext_vector_type(8)));   // 8 bf16 in 4 VGPRs
typedef float f32x4 __attribute__((ext_vector_type(4)));

__device__ __forceinline__ unsigned short f2bf(float f) {   // RNE
  union { float f; unsigned u; } v; v.f = f;
  unsigned u = v.u;
  return (unsigned short)((u + 0x7fffu + ((u >> 16) & 1u)) >> 16);
}
__device__ __forceinline__ float bf2f(unsigned short u) {
  union { unsigned u; float f; } v; v.u = (unsigned)u << 16; return v.f;
}

// ---------------- Big-tile bf16 MFMA GEMM, bf16 output ----------------
// 128x128 tile, BK=32, 4 waves each owning a 64x64 quadrant (4x4 accs).
__global__ __launch_bounds__(256) void gemm_big_h(const unsigned short* __restrict__ A,
    const unsigned short* __restrict__ B, unsigned short* __restrict__ C, int M, int N, int K) {
  __shared__ unsigned short As[128][36];
  __shared__ unsigned short Bs[128][36];
  const int tid = threadIdx.x;
  const int wave = tid >> 6;
  const int lane = tid & 63;
  const int wm = wave & 1;
  const int wn = wave >> 1;
  const int r16 = lane & 15;
  const int quad = lane >> 4;
  const int bm = blockIdx.x * 128;
  const int bn = blockIdx.y * 128;
  const int srow = tid >> 2;
  const int scol = (tid & 3) * 8;
  int ar0 = bm + srow;      if (ar0 >= M) ar0 = M - 1;
  int ar1 = bm + 64 + srow; if (ar1 >= M) ar1 = M - 1;
  const unsigned short* Ag0 = A + (size_t)ar0 * K + scol;
  const unsigned short* Ag1 = A + (size_t)ar1 * K + scol;
  const unsigned short* Bg0 = B + (size_t)(bn + srow) * K + scol;
  const unsigned short* Bg1 = B + (size_t)(bn + 64 + srow) * K + scol;
  f32x4 acc[4][4] = {};
  for (int k0 = 0; k0 < K; k0 += 32) {
    bf16x8 a0 = *(const bf16x8*)(Ag0 + k0);
    bf16x8 a1 = *(const bf16x8*)(Ag1 + k0);
    bf16x8 b0 = *(const bf16x8*)(Bg0 + k0);
    bf16x8 b1 = *(const bf16x8*)(Bg1 + k0);
    __syncthreads();
    *(bf16x8*)(&As[srow][scol]) = a0;
    *(bf16x8*)(&As[64 + srow][scol]) = a1;
    *(bf16x8*)(&Bs[srow][scol]) = b0;
    *(bf16x8*)(&Bs[64 + srow][scol]) = b1;
    __syncthreads();
    bf16x8 af[4], bfr[4];
#pragma unroll
    for (int mi = 0; mi < 4; ++mi)
      af[mi] = *(const bf16x8*)(&As[wm * 64 + mi * 16 + r16][quad * 8]);
#pragma unroll
    for (int ni = 0; ni < 4; ++ni)
      bfr[ni] = *(const bf16x8*)(&Bs[wn * 64 + ni * 16 + r16][quad * 8]);
#pragma unroll
    for (int mi = 0; mi < 4; ++mi)
#pragma unroll
      for (int ni = 0; ni < 4; ++ni)
        acc[mi][ni] = __builtin_amdgcn_mfma_f32_16x16x32_bf16(af[mi], bfr[ni], acc[mi][ni], 0, 0, 0);
  }
#pragma unroll
  for (int mi = 0; mi < 4; ++mi)
#pragma unroll
    for (int ni = 0; ni < 4; ++ni)
#pragma unroll
      for (int r = 0; r < 4; ++r) {
        int row = bm + wm * 64 + mi * 16 + quad * 4 + r;
        if (row < M)
          C[(size_t)row * N + bn + wn * 64 + ni * 16 + r16] = f2bf(acc[mi][ni][r]);
      }
}

// ---------------- Big-tile bf16 MFMA GEMM, fp32 output (residual o2) ----------------
__global__ __launch_bounds__(256) void gemm_big(const unsigned short* __restrict__ A,
    const unsigned short* __restrict__ B, float* __restrict__ C, int M, int N, int K) {
  __shared__ unsigned short As[128][36];
  __shared__ unsigned short Bs[128][36];
  const int tid = threadIdx.x;
  const int wave = tid >> 6;
  const int lane = tid & 63;
  const int wm = wave & 1;
  const int wn = wave >> 1;
  const int r16 = lane & 15;
  const int quad = lane >> 4;
  const int bm = blockIdx.x * 128;
  const int bn = blockIdx.y * 128;
  const int srow = tid >> 2;
  const int scol = (tid & 3) * 8;
  int ar0 = bm + srow;      if (ar0 >= M) ar0 = M - 1;
  int ar1 = bm + 64 + srow; if (ar1 >= M) ar1 = M - 1;
  const unsigned short* Ag0 = A + (size_t)ar0 * K + scol;
  const unsigned short* Ag1 = A + (size_t)ar1 * K + scol;
  const unsigned short* Bg0 = B + (size_t)(bn + srow) * K + scol;
  const unsigned short* Bg1 = B + (size_t)(bn + 64 + srow) * K + scol;
  f32x4 acc[4][4] = {};
  for (int k0 = 0; k0 < K; k0 += 32) {
    bf16x8 a0 = *(const bf16x8*)(Ag0 + k0);
    bf16x8 a1 = *(const bf16x8*)(Ag1 + k0);
    bf16x8 b0 = *(const bf16x8*)(Bg0 + k0);
    bf16x8 b1 = *(const bf16x8*)(Bg1 + k0);
    __syncthreads();
    *(bf16x8*)(&As[srow][scol]) = a0;
    *(bf16x8*)(&As[64 + srow][scol]) = a1;
    *(bf16x8*)(&Bs[srow][scol]) = b0;
    *(bf16x8*)(&Bs[64 + srow][scol]) = b1;
    __syncthreads();
    bf16x8 af[4], bfr[4];
#pragma unroll
    for (int mi = 0; mi < 4; ++mi)
      af[mi] = *(const bf16x8*)(&As[wm * 64 + mi * 16 + r16][quad * 8]);
#pragma unroll
    for (int ni = 0; ni < 4; ++ni)
      bfr[ni] = *(const bf16x8*)(&Bs[wn * 64 + ni * 16 + r16][quad * 8]);
#pragma unroll
    for (int mi = 0; mi < 4; ++mi)
#pragma unroll
      for (int ni = 0; ni < 4; ++ni)
        acc[mi][ni] = __builtin_amdgcn_mfma_f32_16x16x32_bf16(af[mi], bfr[ni], acc[mi][ni], 0, 0, 0);
  }
#pragma unroll
  for (int mi = 0; mi < 4; ++mi)
#pragma unroll
    for (int ni = 0; ni < 4; ++ni)
#pragma unroll
      for (int r = 0; r < 4; ++r) {
        int row = bm + wm * 64 + mi * 16 + quad * 4 + r;
        if (row < M)
          C[(size_t)row * N + bn + wn * 64 + ni * 16 + r16] = acc[mi][ni][r];
      }
}

// ---------------- 64x64 bf16 MFMA GEMM, fp32 out (N=64 P-projections) ----------------
__global__ __launch_bounds__(256) void gemm_bf16t(const unsigned short* __restrict__ A,
    const unsigned short* __restrict__ B, float* __restrict__ C, int M, int N, int K) {
  __shared__ unsigned short As[64][40];
  __shared__ unsigned short Bs[64][40];
  const int tid = threadIdx.x;
  const int wave = tid >> 6;
  const int lane = tid & 63;
  const int wm = wave & 1;
  const int wn = wave >> 1;
  const int r16 = lane & 15;
  const int quad = lane >> 4;
  const int bm = blockIdx.x * 64;
  const int bn = blockIdx.y * 64;
  const int srow = tid >> 2;
  const int schunk = tid & 3;
  int arow = bm + srow; if (arow >= M) arow = M - 1;
  const unsigned short* Ag = A + (size_t)arow * K + schunk * 8;
  const unsigned short* Bg = B + (size_t)(bn + srow) * K + schunk * 8;
  f32x4 acc[2][2] = {};
  for (int k0 = 0; k0 < K; k0 += 32) {
    bf16x8 av = *(const bf16x8*)(Ag + k0);
    bf16x8 bv = *(const bf16x8*)(Bg + k0);
    __syncthreads();
    *(bf16x8*)(&As[srow][schunk * 8]) = av;
    *(bf16x8*)(&Bs[srow][schunk * 8]) = bv;
    __syncthreads();
    bf16x8 af0 = *(const bf16x8*)(&As[wm * 32 + r16][quad * 8]);
    bf16x8 af1 = *(const bf16x8*)(&As[wm * 32 + 16 + r16][quad * 8]);
    bf16x8 bf0 = *(const bf16x8*)(&Bs[wn * 32 + r16][quad * 8]);
    bf16x8 bf1 = *(const bf16x8*)(&Bs[wn * 32 + 16 + r16][quad * 8]);
    acc[0][0] = __builtin_amdgcn_mfma_f32_16x16x32_bf16(af0, bf0, acc[0][0], 0, 0, 0);
    acc[0][1] = __builtin_amdgcn_mfma_f32_16x16x32_bf16(af0, bf1, acc[0][1], 0, 0, 0);
    acc[1][0] = __builtin_amdgcn_mfma_f32_16x16x32_bf16(af1, bf0, acc[1][0], 0, 0, 0);
    acc[1][1] = __builtin_amdgcn_mfma_f32_16x16x32_bf16(af1, bf1, acc[1][1], 0, 0, 0);
  }
#pragma unroll
  for (int mi = 0; mi < 2; ++mi)
#pragma unroll
    for (int ni = 0; ni < 2; ++ni)
#pragma unroll
      for (int r = 0; r < 4; ++r) {
        int row = bm + wm * 32 + mi * 16 + quad * 4 + r;
        if (row < M)
          C[(size_t)row * N + bn + wn * 32 + ni * 16 + r16] = acc[mi][ni][r];
      }
}

// ---------------- fp32 tiled GEMM (tiny M1/M2 precompute) ----------------
__global__ __launch_bounds__(256) void gemm_abt(const float* __restrict__ A,
    const float* __restrict__ B, float* __restrict__ C, int M, int N, int K) {
  __shared__ float As[32][64];
  __shared__ float Bs[32][64];
  const int tid = threadIdx.x;
  const int bm = blockIdx.y * 64;
  const int bn = blockIdx.x * 64;
  const int tx = tid & 15;
  const int ty = tid >> 4;
  const int lr = tid & 63;
  const int lq = tid >> 6;
  float acc[4][4] = {};
  for (int k0 = 0; k0 < K; k0 += 32) {
#pragma unroll
    for (int s = 0; s < 2; ++s) {
      const int q = lq + s * 4;
      const int gm = bm + lr;
      float4 va = make_float4(0.f, 0.f, 0.f, 0.f);
      if (gm < M) va = *(const float4*)(A + (size_t)gm * K + k0 + q * 4);
      As[q * 4 + 0][lr] = va.x; As[q * 4 + 1][lr] = va.y;
      As[q * 4 + 2][lr] = va.z; As[q * 4 + 3][lr] = va.w;
      const int gn = bn + lr;
      float4 vb = *(const float4*)(B + (size_t)gn * K + k0 + q * 4);
      Bs[q * 4 + 0][lr] = vb.x; Bs[q * 4 + 1][lr] = vb.y;
      Bs[q * 4 + 2][lr] = vb.z; Bs[q * 4 + 3][lr] = vb.w;
    }
    __syncthreads();
#pragma unroll
    for (int kk = 0; kk < 32; ++kk) {
      float a[4], b[4];
#pragma unroll
      for (int i2 = 0; i2 < 4; ++i2) { a[i2] = As[kk][ty * 4 + i2]; b[i2] = Bs[kk][tx * 4 + i2]; }
#pragma unroll
      for (int i2 = 0; i2 < 4; ++i2)
#pragma unroll
        for (int j2 = 0; j2 < 4; ++j2)
          acc[i2][j2] = fmaf(a[i2], b[j2], acc[i2][j2]);
    }
    __syncthreads();
  }
#pragma unroll
  for (int i2 = 0; i2 < 4; ++i2) {
    const int gm = bm + ty * 4 + i2;
    if (gm >= M) continue;
#pragma unroll
    for (int j2 = 0; j2 < 4; ++j2)
      C[(size_t)gm * N + bn + tx * 4 + j2] = acc[i2][j2];
  }
}

// ---------------- Fused prep: all bf16 conversions + LoRA re-layouts ----------------
__global__ void prep_all(const float* __restrict__ x0, const float* __restrict__ W1,
    const float* __restrict__ W2, const float* __restrict__ res_W,
    const float* __restrict__ A1, const float* __restrict__ A2,
    const float* __restrict__ B1, const float* __restrict__ B2,
    unsigned short* __restrict__ x0b, unsigned short* __restrict__ W1b,
    unsigned short* __restrict__ W2b, unsigned short* __restrict__ resWb,
    float* __restrict__ Amat1, float* __restrict__ Amat2,
    unsigned short* __restrict__ Bmat1b, unsigned short* __restrict__ Bmat2b, int nx0) {
  int idx = blockIdx.x * 256 + threadIdx.x;
  if (idx < nx0) { x0b[idx] = f2bf(x0[idx]); return; } idx -= nx0;
  if (idx < D2 * EMB) { W1b[idx] = f2bf(W1[idx]); return; } idx -= D2 * EMB;
  if (idx < OUTD * D2) { W2b[idx] = f2bf(W2[idx]); return; } idx -= OUTD * D2;
  if (idx < OUTD * EMB) { resWb[idx] = f2bf(res_W[idx]); return; } idx -= OUTD * EMB;
  if (idx < 64 * EMB) { int d = idx % EMB, rk = idx / EMB, k = rk & 7, r = rk >> 3;
    Amat1[idx] = A1[(size_t)r * EMB * RANK + (size_t)d * RANK + k]; return; } idx -= 64 * EMB;
  if (idx < 64 * D2) { int d = idx % D2, rk = idx / D2, k = rk & 7, r = rk >> 3;
    Amat2[idx] = A2[(size_t)r * D2 * RANK + (size_t)d * RANK + k]; return; } idx -= 64 * D2;
  if (idx < 64 * EMB) { int d = idx % EMB, rk = idx / EMB, k = rk & 7, r = rk >> 3;
    Bmat1b[idx] = f2bf(B1[(size_t)r * EMB * RANK + (size_t)d * RANK + k]); return; } idx -= 64 * EMB;
  if (idx < 64 * D2) { int d = idx % D2, rk = idx / D2, k = rk & 7, r = rk >> 3;
    Bmat2b[idx] = f2bf(B2[(size_t)r * D2 * RANK + (size_t)d * RANK + k]); }
}

// ---------------- Matt folds (block 0: layer1, block 1: layer2) ----------------
__global__ void fold_att(const float* __restrict__ M1, const float* __restrict__ attR1,
                         const float* __restrict__ M2, const float* __restrict__ attR2,
                         float* __restrict__ Matt1, float* __restrict__ Matt2) {
  int t = threadIdx.x;
  if (blockIdx.x == 0) {
    int h = t & 3, rk = t >> 2;
    float s = 0.f;
    for (int c = 0; c < HID; ++c)
      s = fmaf(M1[(size_t)rk * D2 + h * HID + c], attR1[h * HID + c], s);
    Matt1[rk * 4 + h] = s;
  } else if (t < 64) {
    float s = 0.f;
    for (int c = 0; c < OUTD; ++c) s = fmaf(M2[(size_t)t * OUTD + c], attR2[c], s);
    Matt2[t] = s;
  }
}

// ---------------- Transpose M1/M2 -> bf16 [c][rk] ----------------
__global__ void transpose_Mb(const float* __restrict__ M1, const float* __restrict__ M2,
                             unsigned short* __restrict__ M1tb, unsigned short* __restrict__ M2tb) {
  int idx = blockIdx.x * 256 + threadIdx.x;
  if (idx < 64 * D2) {
    int rk = idx / D2, c = idx % D2;
    M1tb[c * 64 + rk] = f2bf(M1[idx]);
  } else {
    idx -= 64 * D2;
    if (idx < 64 * OUTD) {
      int rk = idx / OUTD, c = idx % OUTD;
      M2tb[c * 64 + rk] = f2bf(M2[idx]);
    }
  }
}

// ---------------- Coalesced rowdots (wave per row, shuffle reduce) ----------------
__global__ __launch_bounds__(256) void rowdot1_fast(const unsigned short* __restrict__ Z,
    const float* __restrict__ attL, const float* __restrict__ attR,
    float* __restrict__ al, float* __restrict__ ar, int Nn) {
  int wi = blockIdx.x * 4 + (threadIdx.x >> 6);   // (n,h), total Nn*4
  int lane = threadIdx.x & 63;
  if (wi >= Nn * 4) return;
  int n = wi >> 2, h = wi & 3;
  const ushort2* z = (const ushort2*)(Z + (size_t)n * D2 + h * HID);
  ushort2 zv = z[lane];
  float2 L = ((const float2*)(attL + h * HID))[lane];
  float2 R = ((const float2*)(attR + h * HID))[lane];
  float z0 = bf2f(zv.x), z1 = bf2f(zv.y);
  float sl = z0 * L.x + z1 * L.y;
  float sr = z0 * R.x + z1 * R.y;
  for (int o = 32; o > 0; o >>= 1) { sl += __shfl_down(sl, o, 64); sr += __shfl_down(sr, o, 64); }
  if (lane == 0) { al[wi] = sl; ar[wi] = sr; }
}

__global__ __launch_bounds__(256) void rowdot2_fast(const unsigned short* __restrict__ Z,
    const float* __restrict__ attL, const float* __restrict__ attR,
    float* __restrict__ al, float* __restrict__ ar, int Nn) {
  int n = blockIdx.x * 4 + (threadIdx.x >> 6);
  int lane = threadIdx.x & 63;
  if (n >= Nn) return;
  const uint2* z = (const uint2*)(Z + (size_t)n * OUTD);
  uint2 zv = z[lane];
  float4 L = ((const float4*)attL)[lane];
  float4 R = ((const float4*)attR)[lane];
  float z0 = bf2f((unsigned short)(zv.x & 0xffff)), z1 = bf2f((unsigned short)(zv.x >> 16));
  float z2 = bf2f((unsigned short)(zv.y & 0xffff)), z3 = bf2f((unsigned short)(zv.y >> 16));
  float sl = z0 * L.x + z1 * L.y + z2 * L.z + z3 * L.w;
  float sr = z0 * R.x + z1 * R.y + z2 * R.z + z3 * R.w;
  for (int o = 32; o > 0; o >>= 1) { sl += __shfl_down(sl, o, 64); sr += __shfl_down(sr, o, 64); }
  if (lane == 0) { al[n] = sl; ar[n] = sr; }
}

// ---------------- CSR build ----------------
__global__ void hist_kernel(const int* __restrict__ ii, int* __restrict__ deg, int E) {
  int e = blockIdx.x * blockDim.x + threadIdx.x;
  if (e < E) atomicAdd(&deg[ii[e]], 1);
}

__global__ __launch_bounds__(1024) void exscan_kernel(const int* __restrict__ deg,
                                                      int* __restrict__ rowstart, int n) {
  __shared__ int wsum[16];
  int t = threadIdx.x;
  int lane = t & 63, wid = t >> 6;
  int carry = 0;   // live only in thread 0
  for (int base = 0; base < n; base += 1024) {
    int v = (base + t < n) ? deg[base + t] : 0;
    int x = v;
#pragma unroll
    for (int o = 1; o < 64; o <<= 1) {
      int y = __shfl_up(x, o, 64);
      if (lane >= o) x += y;
    }
    if (lane == 63) wsum[wid] = x;
    __syncthreads();
    if (t == 0) {
      int s = carry;
      for (int w2 = 0; w2 < 16; ++w2) { int tmp = wsum[w2]; wsum[w2] = s; s += tmp; }
      carry = s;
    }
    __syncthreads();
    int incl = x + wsum[wid];
    if (base + t < n) rowstart[base + t] = incl - v;
    __syncthreads();   // protect wsum before next chunk overwrite
  }
  if (t == 0) rowstart[n] = carry;
}

__global__ void scatter_kernel(const int* __restrict__ ii, const int* __restrict__ rowstart,
                               int* __restrict__ cursor, int* __restrict__ eid,
                               int* __restrict__ slot_of, int E) {
  int e = blockIdx.x * blockDim.x + threadIdx.x;
  if (e >= E) return;
  int i = ii[e];
  int p = atomicAdd(&cursor[i], 1);
  int s = rowstart[i] + p;
  eid[s] = e;
  slot_of[e] = s;
}

// ---------------- Layer-1 edge logits -> packed records at CSR slots ----------------
// rec1 (16 floats): [j, rt, ex0, ex1 | ex2, ex3, low0, low1 | low2..low5 | low6, low7, 0, 0]
__global__ void edge_alpha1(const int* __restrict__ ji, const int* __restrict__ ii,
                            const int* __restrict__ et, const int* __restrict__ slot_of,
                            const float* __restrict__ P1,
                            const float* __restrict__ al1, const float* __restrict__ ar1,
                            const float* __restrict__ relb1, const float* __restrict__ Matt1,
                            float4* __restrict__ recs1, int E) {
  int e = blockIdx.x * blockDim.x + threadIdx.x;
  if (e >= E) return;
  int j = ji[e], i = ii[e], rt = et[e];
  float low[RANK];
#pragma unroll
  for (int k = 0; k < RANK; ++k) low[k] = P1[(size_t)j * 64 + rt * RANK + k];
  float exv[HEADS];
#pragma unroll
  for (int h = 0; h < HEADS; ++h) {
    float a = al1[i * 4 + h] + ar1[j * 4 + h] + relb1[rt * 4 + h];
#pragma unroll
    for (int k = 0; k < RANK; ++k) a = fmaf(low[k], Matt1[(rt * RANK + k) * 4 + h], a);
    a = (a > 0.f) ? a : NEG_SLOPE * a;
    exv[h] = expf(a);
  }
  float4* rp = recs1 + (size_t)slot_of[e] * 4;
  rp[0] = make_float4(__int_as_float(j), __int_as_float(rt), exv[0], exv[1]);
  rp[1] = make_float4(exv[2], exv[3], low[0], low[1]);
  rp[2] = make_float4(low[2], low[3], low[4], low[5]);
  rp[3] = make_float4(low[6], low[7], 0.f, 0.f);
}

// ---------------- Layer-1 CSR gather (records + bf16 z + vectorized M) ----------------
__global__ __launch_bounds__(256) void node_agg1(const float4* __restrict__ recs1,
    const int* __restrict__ rowstart, const unsigned short* __restrict__ z1b,
    const unsigned short* __restrict__ M1tb, const float* __restrict__ bias1,
    unsigned short* __restrict__ h1out, int Nn) {
  int i = blockIdx.x;
  int t = threadIdx.x;
  int s0 = rowstart[i], s1 = rowstart[i + 1];
  int deg = s1 - s0;
  __shared__ float s_den[NRELS * HEADS];
  if (t < NRELS * HEADS) s_den[t] = 0.f;
  __syncthreads();
  const float* rf = (const float*)recs1;
  for (int q = t; q < deg * HEADS; q += 256) {
    int p = q >> 2, h = q & 3;
    size_t base = (size_t)(s0 + p) * 16;
    int rt = __float_as_int(rf[base + 1]);
    atomicAdd(&s_den[rt * 4 + h], rf[base + 2 + h]);
  }
  __syncthreads();
  const int c0 = t, c1 = t + 256;
  const bool hi = (t & 128) != 0;     // selects head within each half
  float acc0 = 0.f, acc1 = 0.f;
  for (int p = 0; p < deg; ++p) {
    const float4* rp = recs1 + (size_t)(s0 + p) * 4;
    float4 r0 = rp[0];
    float4 r1 = rp[1];
    float4 r2 = rp[2];
    float4 r3 = rp[3];
    int j = __float_as_int(r0.x);
    int rt = __float_as_int(r0.y);
    float exa = hi ? r0.w : r0.z;     // head 1 : 0
    float exb = hi ? r1.y : r1.x;     // head 3 : 2
    float low[RANK] = {r1.z, r1.w, r2.x, r2.y, r2.z, r2.w, r3.x, r3.y};
    float w0 = exa / s_den[rt * 4 + (hi ? 1 : 0)];
    float w1 = exb / s_den[rt * 4 + (hi ? 3 : 2)];
    const unsigned short* zr = z1b + (size_t)j * D2;
    float v0 = bf2f(zr[c0]);
    float v1 = bf2f(zr[c1]);
    bf16x8 m0 = *(const bf16x8*)(M1tb + (size_t)c0 * 64 + rt * 8);
    bf16x8 m1 = *(const bf16x8*)(M1tb + (size_t)c1 * 64 + rt * 8);
#pragma unroll
    for (int k = 0; k < RANK; ++k) {
      v0 = fmaf(low[k], bf2f((unsigned short)m0[k]), v0);
      v1 = fmaf(low[k], bf2f((unsigned short)m1[k]), v1);
    }
    acc0 = fmaf(w0, v0, acc0);
    acc1 = fmaf(w1, v1, acc1);
  }
  float r0v = acc0 + bias1[c0];
  float r1v = acc1 + bias1[c1];
  h1out[(size_t)i * D2 + c0] = f2bf(r0v > 0.f ? r0v : expm1f(r0v));
  h1out[(size_t)i * D2 + c1] = f2bf(r1v > 0.f ? r1v : expm1f(r1v));
}

// ---------------- Layer-2 edge logits -> packed records ----------------
// rec2 (12 floats): [j, rt, ex, low0 | low1..low4 | low5, low6, low7, 0]
__global__ void edge_alpha2(const int* __restrict__ ji, const int* __restrict__ ii,
                            const int* __restrict__ et, const int* __restrict__ slot_of,
                            const float* __restrict__ P2,
                            const float* __restrict__ al2, const float* __restrict__ ar2,
                            const float* __restrict__ relb2, const float* __restrict__ Matt2,
                            float4* __restrict__ recs2, int E) {
  int e = blockIdx.x * blockDim.x + threadIdx.x;
  if (e >= E) return;
  int j = ji[e], i = ii[e], rt = et[e];
  float low[RANK];
#pragma unroll
  for (int k = 0; k < RANK; ++k) low[k] = P2[(size_t)j * 64 + rt * RANK + k];
  float a = al2[i] + ar2[j] + relb2[rt];
#pragma unroll
  for (int k = 0; k < RANK; ++k) a = fmaf(low[k], Matt2[rt * RANK + k], a);
  a = (a > 0.f) ? a : NEG_SLOPE * a;
  float ex = expf(a);
  float4* rp = recs2 + (size_t)slot_of[e] * 3;
  rp[0] = make_float4(__int_as_float(j), __int_as_float(rt), ex, low[0]);
  rp[1] = make_float4(low[1], low[2], low[3], low[4]);
  rp[2] = make_float4(low[5], low[6], low[7], 0.f);
}

// ---------------- Layer-2 CSR gather + residual + bias + LayerNorm -> out ----------------
__global__ __launch_bounds__(256) void node_agg2(const float4* __restrict__ recs2,
    const int* __restrict__ rowstart, const unsigned short* __restrict__ z2b,
    const unsigned short* __restrict__ M2tb, const float* __restrict__ res,
    const float* __restrict__ bias2, const float* __restrict__ res_b,
    const float* __restrict__ ln_g, const float* __restrict__ ln_b,
    float* __restrict__ y, int Nn) {
  int i = blockIdx.x;
  int t = threadIdx.x;
  int s0 = rowstart[i], s1 = rowstart[i + 1];
  int deg = s1 - s0;
  __shared__ float s_den[NRELS];
  __shared__ float red[256];
  if (t < NRELS) s_den[t] = 0.f;
  __syncthreads();
  const float* rf = (const float*)recs2;
  for (int q = t; q < deg; q += 256) {
    size_t base = (size_t)(s0 + q) * 12;
    int rt = __float_as_int(rf[base + 1]);
    atomicAdd(&s_den[rt], rf[base + 2]);
  }
  __syncthreads();
  float acc = 0.f;
  for (int p = 0; p < deg; ++p) {
    const float4* rp = recs2 + (size_t)(s0 + p) * 3;
    float4 r0 = rp[0];
    float4 r1 = rp[1];
    float4 r2 = rp[2];
    int j = __float_as_int(r0.x);
    int rt = __float_as_int(r0.y);
    float wgt = r0.z / s_den[rt];
    float low[RANK] = {r0.w, r1.x, r1.y, r1.z, r1.w, r2.x, r2.y, r2.z};
    float v = bf2f(z2b[(size_t)j * OUTD + t]);
    bf16x8 m0 = *(const bf16x8*)(M2tb + (size_t)t * 64 + rt * 8);
#pragma unroll
    for (int k = 0; k < RANK; ++k)
      v = fmaf(low[k], bf2f((unsigned short)m0[k]), v);
    acc = fmaf(wgt, v, acc);
  }
  float v = acc + res[(size_t)i * OUTD + t] + bias2[t] + res_b[t];
  red[t] = v;
  __syncthreads();
  for (int s = 128; s > 0; s >>= 1) { if (t < s) red[t] += red[t + s]; __syncthreads(); }
  float mu = red[0] / OUTD;
  __syncthreads();
  float d = v - mu;
  red[t] = d * d;
  __syncthreads();
  for (int s = 128; s > 0; s >>= 1) { if (t < s) red[t] += red[t + s]; __syncthreads(); }
  float var = red[0] / OUTD;
  y[(size_t)i * OUTD + t] = d * rsqrtf(var + LN_EPS) * ln_g[t] + ln_b[t];
}

extern "C" void kernel_launch(void* const* d_in, const int* in_sizes, int n_in,
                              void* d_out, int out_size, void* d_ws, size_t ws_size,
                              hipStream_t stream) {
  const float* x0     = (const float*)d_in[0];
  const float* A1     = (const float*)d_in[1];
  const float* B1     = (const float*)d_in[2];
  const float* W1     = (const float*)d_in[3];
  const float* attL1  = (const float*)d_in[4];
  const float* attR1  = (const float*)d_in[5];
  const float* relb1  = (const float*)d_in[6];
  const float* bias1  = (const float*)d_in[7];
  const float* A2     = (const float*)d_in[8];
  const float* B2     = (const float*)d_in[9];
  const float* W2     = (const float*)d_in[10];
  const float* attL2  = (const float*)d_in[11];
  const float* attR2  = (const float*)d_in[12];
  const float* relb2  = (const float*)d_in[13];
  const float* bias2  = (const float*)d_in[14];
  const float* res_W  = (const float*)d_in[15];
  const float* res_b  = (const float*)d_in[16];
  const float* ln_g   = (const float*)d_in[17];
  const float* ln_b   = (const float*)d_in[18];
  const int*   eidx   = (const int*)d_in[19];
  const int*   etype  = (const int*)d_in[20];
  float* out = (float*)d_out;

  const int Nn = in_sizes[0] / EMB;     // 30000
  const int E  = in_sizes[20];          // 150000
  const int* ji = eidx;
  const int* ii = eidx + E;

  // ---- workspace carve-up (float units; 16B alignment preserved) ----
  float* w = (float*)d_ws;
  size_t off = 0;
  float* o2    = w + off; off += (size_t)Nn * OUTD;      // residual GEMM (fp32)
  float* P1    = w + off; off += (size_t)Nn * 64;
  float* P2    = w + off; off += (size_t)Nn * 64;
  float* M1    = w + off; off += 64 * D2;
  float* M2    = w + off; off += 64 * OUTD;
  float* Amat1 = w + off; off += 64 * EMB;
  float* Amat2 = w + off; off += 64 * D2;
  float* Matt1 = w + off; off += 64 * 4;
  float* Matt2 = w + off; off += 64;
  float* al1   = w + off; off += (size_t)Nn * 4;
  float* ar1   = w + off; off += (size_t)Nn * 4;
  float* al2   = w + off; off += (size_t)Nn;
  float* ar2   = w + off; off += (size_t)Nn;
  float4* recs1 = (float4*)(w + off); off += (size_t)E * 16;
  float4* recs2 = (float4*)(w + off); off += (size_t)E * 12;
  unsigned short* z1b    = (unsigned short*)(w + off); off += (size_t)Nn * D2 / 2;
  unsigned short* z2b    = (unsigned short*)(w + off); off += (size_t)Nn * OUTD / 2;
  unsigned short* x0b    = (unsigned short*)(w + off); off += (size_t)Nn * EMB / 2;
  unsigned short* h1b    = (unsigned short*)(w + off); off += (size_t)Nn * D2 / 2;
  unsigned short* W1b    = (unsigned short*)(w + off); off += (size_t)D2 * EMB / 2;
  unsigned short* W2b    = (unsigned short*)(w + off); off += (size_t)OUTD * D2 / 2;
  unsigned short* resWb  = (unsigned short*)(w + off); off += (size_t)OUTD * EMB / 2;
  unsigned short* Bmat1b = (unsigned short*)(w + off); off += (size_t)64 * EMB / 2;
  unsigned short* Bmat2b = (unsigned short*)(w + off); off += (size_t)64 * D2 / 2;
  unsigned short* M1tb   = (unsigned short*)(w + off); off += (size_t)64 * D2 / 2;
  unsigned short* M2tb   = (unsigned short*)(w + off); off += (size_t)64 * OUTD / 2;
  int* ideg     = (int*)(w + off); off += (size_t)Nn;
  int* cursor   = (int*)(w + off); off += (size_t)Nn;
  int* slot_of  = (int*)(w + off); off += (size_t)E;
  int* eid      = (int*)(w + off); off += (size_t)E;
  int* rowstart = (int*)(w + off); off += (size_t)Nn + 1;
  (void)ws_size; (void)n_in; (void)out_size;

  const int MT64 = (Nn + 63) / 64;
  const int MT128 = (Nn + 127) / 128;

  // 0) CSR build
  (void)hipMemsetAsync(ideg, 0, (size_t)Nn * sizeof(int), stream);
  (void)hipMemsetAsync(cursor, 0, (size_t)Nn * sizeof(int), stream);
  hist_kernel<<<(E + 255) / 256, 256, 0, stream>>>(ii, ideg, E);
  exscan_kernel<<<1, 1024, 0, stream>>>(ideg, rowstart, Nn);
  scatter_kernel<<<(E + 255) / 256, 256, 0, stream>>>(ii, rowstart, cursor, eid, slot_of, E);

  // 1) fused conversions + LoRA re-layouts
  {
    int nx0 = Nn * EMB;
    int total = nx0 + D2 * EMB + OUTD * D2 + OUTD * EMB + 64 * EMB + 64 * D2 + 64 * EMB + 64 * D2;
    prep_all<<<(total + 255) / 256, 256, 0, stream>>>(x0, W1, W2, res_W, A1, A2, B1, B2,
        x0b, W1b, W2b, resWb, Amat1, Amat2, Bmat1b, Bmat2b, nx0);
  }

  // 2) M1 = Amat1 @ W1^T ; M2 = Amat2 @ W2^T ; Matt folds ; transposed bf16 copies
  gemm_abt<<<dim3(D2 / 64, 1), 256, 0, stream>>>(Amat1, W1, M1, 64, D2, EMB);
  gemm_abt<<<dim3(OUTD / 64, 1), 256, 0, stream>>>(Amat2, W2, M2, 64, OUTD, D2);
  fold_att<<<2, 256, 0, stream>>>(M1, attR1, M2, attR2, Matt1, Matt2);
  transpose_Mb<<<(64 * D2 + 64 * OUTD + 255) / 256, 256, 0, stream>>>(M1, M2, M1tb, M2tb);

  // 3) Layer-1 node GEMMs
  gemm_big_h<<<dim3(MT128, D2 / 128), 256, 0, stream>>>(x0b, W1b, z1b, Nn, D2, EMB);
  gemm_bf16t<<<dim3(MT64, 1), 256, 0, stream>>>(x0b, Bmat1b, P1, Nn, 64, EMB);

  // 4) attention dots (coalesced wave-reduce)
  rowdot1_fast<<<Nn, 256, 0, stream>>>(z1b, attL1, attR1, al1, ar1, Nn);

  // 5) Layer-1 edge logits -> records; CSR gather
  edge_alpha1<<<(E + 255) / 256, 256, 0, stream>>>(ji, ii, etype, slot_of, P1, al1, ar1,
                                                   relb1, Matt1, recs1, E);
  node_agg1<<<Nn, 256, 0, stream>>>(recs1, rowstart, z1b, M1tb, bias1, h1b, Nn);

  // 6) Layer-2 node GEMMs + residual
  gemm_big_h<<<dim3(MT128, OUTD / 128), 256, 0, stream>>>(h1b, W2b, z2b, Nn, OUTD, D2);
  gemm_bf16t<<<dim3(MT64, 1), 256, 0, stream>>>(h1b, Bmat2b, P2, Nn, 64, D2);
  gemm_big<<<dim3(MT128, OUTD / 128), 256, 0, stream>>>(x0b, resWb, o2, Nn, OUTD, EMB);

  // 7) Layer-2 attention dots
  rowdot2_fast<<<(Nn + 3) / 4, 256, 0, stream>>>(z2b, attL2, attR2, al2, ar2, Nn);

  // 8) Layer-2 edge logits -> records; CSR gather + residual + LN
  edge_alpha2<<<(E + 255) / 256, 256, 0, stream>>>(ji, ii, etype, slot_of, P2, al2, ar2,
                                                   relb2, Matt2, recs2, E);
  node_agg2<<<Nn, 256, 0, stream>>>(recs2, rowstart, z2b, M2tb, o2, bias2, res_b,
                                    ln_g, ln_b, out, Nn);
}

// Round 9
// 502.897 us; speedup vs baseline: 1.3827x; 1.3827x over previous
//
#include <hip/hip_runtime.h>
#include <cstddef>

#define NRELS 8
#define EMB 128
#define HID 128
#define OUTD 256
#define HEADS 4
#define RANK 8
#define D2 512            // HEADS*HID, conv2 input dim
#define NEG_SLOPE 0.2f
#define LN_EPS 1e-5f

typedef short bf16x8 __attribute__((ext_vector_type(8)));   // 8 bf16 in 4 VGPRs
typedef float f32x4 __attribute__((ext_vector_type(4)));

__device__ __forceinline__ unsigned short f2bf(float f) {   // RNE
  union { float f; unsigned u; } v; v.f = f;
  unsigned u = v.u;
  return (unsigned short)((u + 0x7fffu + ((u >> 16) & 1u)) >> 16);
}
__device__ __forceinline__ float bf2f(unsigned short u) {
  union { unsigned u; float f; } v; v.u = (unsigned)u << 16; return v.f;
}

// ---------------- Big-tile bf16 MFMA GEMM, bf16 output ----------------
__global__ __launch_bounds__(256) void gemm_big_h(const unsigned short* __restrict__ A,
    const unsigned short* __restrict__ B, unsigned short* __restrict__ C, int M, int N, int K) {
  __shared__ unsigned short As[128][36];
  __shared__ unsigned short Bs[128][36];
  const int tid = threadIdx.x;
  const int wave = tid >> 6;
  const int lane = tid & 63;
  const int wm = wave & 1;
  const int wn = wave >> 1;
  const int r16 = lane & 15;
  const int quad = lane >> 4;
  const int bm = blockIdx.x * 128;
  const int bn = blockIdx.y * 128;
  const int srow = tid >> 2;
  const int scol = (tid & 3) * 8;
  int ar0 = bm + srow;      if (ar0 >= M) ar0 = M - 1;
  int ar1 = bm + 64 + srow; if (ar1 >= M) ar1 = M - 1;
  const unsigned short* Ag0 = A + (size_t)ar0 * K + scol;
  const unsigned short* Ag1 = A + (size_t)ar1 * K + scol;
  const unsigned short* Bg0 = B + (size_t)(bn + srow) * K + scol;
  const unsigned short* Bg1 = B + (size_t)(bn + 64 + srow) * K + scol;
  f32x4 acc[4][4] = {};
  for (int k0 = 0; k0 < K; k0 += 32) {
    bf16x8 a0 = *(const bf16x8*)(Ag0 + k0);
    bf16x8 a1 = *(const bf16x8*)(Ag1 + k0);
    bf16x8 b0 = *(const bf16x8*)(Bg0 + k0);
    bf16x8 b1 = *(const bf16x8*)(Bg1 + k0);
    __syncthreads();
    *(bf16x8*)(&As[srow][scol]) = a0;
    *(bf16x8*)(&As[64 + srow][scol]) = a1;
    *(bf16x8*)(&Bs[srow][scol]) = b0;
    *(bf16x8*)(&Bs[64 + srow][scol]) = b1;
    __syncthreads();
    bf16x8 af[4], bfr[4];
#pragma unroll
    for (int mi = 0; mi < 4; ++mi)
      af[mi] = *(const bf16x8*)(&As[wm * 64 + mi * 16 + r16][quad * 8]);
#pragma unroll
    for (int ni = 0; ni < 4; ++ni)
      bfr[ni] = *(const bf16x8*)(&Bs[wn * 64 + ni * 16 + r16][quad * 8]);
#pragma unroll
    for (int mi = 0; mi < 4; ++mi)
#pragma unroll
      for (int ni = 0; ni < 4; ++ni)
        acc[mi][ni] = __builtin_amdgcn_mfma_f32_16x16x32_bf16(af[mi], bfr[ni], acc[mi][ni], 0, 0, 0);
  }
#pragma unroll
  for (int mi = 0; mi < 4; ++mi)
#pragma unroll
    for (int ni = 0; ni < 4; ++ni)
#pragma unroll
      for (int r = 0; r < 4; ++r) {
        int row = bm + wm * 64 + mi * 16 + quad * 4 + r;
        if (row < M)
          C[(size_t)row * N + bn + wn * 64 + ni * 16 + r16] = f2bf(acc[mi][ni][r]);
      }
}

// ---------------- Big-tile bf16 MFMA GEMM, fp32 output (residual o2) ----------------
__global__ __launch_bounds__(256) void gemm_big(const unsigned short* __restrict__ A,
    const unsigned short* __restrict__ B, float* __restrict__ C, int M, int N, int K) {
  __shared__ unsigned short As[128][36];
  __shared__ unsigned short Bs[128][36];
  const int tid = threadIdx.x;
  const int wave = tid >> 6;
  const int lane = tid & 63;
  const int wm = wave & 1;
  const int wn = wave >> 1;
  const int r16 = lane & 15;
  const int quad = lane >> 4;
  const int bm = blockIdx.x * 128;
  const int bn = blockIdx.y * 128;
  const int srow = tid >> 2;
  const int scol = (tid & 3) * 8;
  int ar0 = bm + srow;      if (ar0 >= M) ar0 = M - 1;
  int ar1 = bm + 64 + srow; if (ar1 >= M) ar1 = M - 1;
  const unsigned short* Ag0 = A + (size_t)ar0 * K + scol;
  const unsigned short* Ag1 = A + (size_t)ar1 * K + scol;
  const unsigned short* Bg0 = B + (size_t)(bn + srow) * K + scol;
  const unsigned short* Bg1 = B + (size_t)(bn + 64 + srow) * K + scol;
  f32x4 acc[4][4] = {};
  for (int k0 = 0; k0 < K; k0 += 32) {
    bf16x8 a0 = *(const bf16x8*)(Ag0 + k0);
    bf16x8 a1 = *(const bf16x8*)(Ag1 + k0);
    bf16x8 b0 = *(const bf16x8*)(Bg0 + k0);
    bf16x8 b1 = *(const bf16x8*)(Bg1 + k0);
    __syncthreads();
    *(bf16x8*)(&As[srow][scol]) = a0;
    *(bf16x8*)(&As[64 + srow][scol]) = a1;
    *(bf16x8*)(&Bs[srow][scol]) = b0;
    *(bf16x8*)(&Bs[64 + srow][scol]) = b1;
    __syncthreads();
    bf16x8 af[4], bfr[4];
#pragma unroll
    for (int mi = 0; mi < 4; ++mi)
      af[mi] = *(const bf16x8*)(&As[wm * 64 + mi * 16 + r16][quad * 8]);
#pragma unroll
    for (int ni = 0; ni < 4; ++ni)
      bfr[ni] = *(const bf16x8*)(&Bs[wn * 64 + ni * 16 + r16][quad * 8]);
#pragma unroll
    for (int mi = 0; mi < 4; ++mi)
#pragma unroll
      for (int ni = 0; ni < 4; ++ni)
        acc[mi][ni] = __builtin_amdgcn_mfma_f32_16x16x32_bf16(af[mi], bfr[ni], acc[mi][ni], 0, 0, 0);
  }
#pragma unroll
  for (int mi = 0; mi < 4; ++mi)
#pragma unroll
    for (int ni = 0; ni < 4; ++ni)
#pragma unroll
      for (int r = 0; r < 4; ++r) {
        int row = bm + wm * 64 + mi * 16 + quad * 4 + r;
        if (row < M)
          C[(size_t)row * N + bn + wn * 64 + ni * 16 + r16] = acc[mi][ni][r];
      }
}

// ---------------- 64x64 bf16 MFMA GEMM, fp32 out (N=64 P-projections) ----------------
__global__ __launch_bounds__(256) void gemm_bf16t(const unsigned short* __restrict__ A,
    const unsigned short* __restrict__ B, float* __restrict__ C, int M, int N, int K) {
  __shared__ unsigned short As[64][40];
  __shared__ unsigned short Bs[64][40];
  const int tid = threadIdx.x;
  const int wave = tid >> 6;
  const int lane = tid & 63;
  const int wm = wave & 1;
  const int wn = wave >> 1;
  const int r16 = lane & 15;
  const int quad = lane >> 4;
  const int bm = blockIdx.x * 64;
  const int bn = blockIdx.y * 64;
  const int srow = tid >> 2;
  const int schunk = tid & 3;
  int arow = bm + srow; if (arow >= M) arow = M - 1;
  const unsigned short* Ag = A + (size_t)arow * K + schunk * 8;
  const unsigned short* Bg = B + (size_t)(bn + srow) * K + schunk * 8;
  f32x4 acc[2][2] = {};
  for (int k0 = 0; k0 < K; k0 += 32) {
    bf16x8 av = *(const bf16x8*)(Ag + k0);
    bf16x8 bv = *(const bf16x8*)(Bg + k0);
    __syncthreads();
    *(bf16x8*)(&As[srow][schunk * 8]) = av;
    *(bf16x8*)(&Bs[srow][schunk * 8]) = bv;
    __syncthreads();
    bf16x8 af0 = *(const bf16x8*)(&As[wm * 32 + r16][quad * 8]);
    bf16x8 af1 = *(const bf16x8*)(&As[wm * 32 + 16 + r16][quad * 8]);
    bf16x8 bf0 = *(const bf16x8*)(&Bs[wn * 32 + r16][quad * 8]);
    bf16x8 bf1 = *(const bf16x8*)(&Bs[wn * 32 + 16 + r16][quad * 8]);
    acc[0][0] = __builtin_amdgcn_mfma_f32_16x16x32_bf16(af0, bf0, acc[0][0], 0, 0, 0);
    acc[0][1] = __builtin_amdgcn_mfma_f32_16x16x32_bf16(af0, bf1, acc[0][1], 0, 0, 0);
    acc[1][0] = __builtin_amdgcn_mfma_f32_16x16x32_bf16(af1, bf0, acc[1][0], 0, 0, 0);
    acc[1][1] = __builtin_amdgcn_mfma_f32_16x16x32_bf16(af1, bf1, acc[1][1], 0, 0, 0);
  }
#pragma unroll
  for (int mi = 0; mi < 2; ++mi)
#pragma unroll
    for (int ni = 0; ni < 2; ++ni)
#pragma unroll
      for (int r = 0; r < 4; ++r) {
        int row = bm + wm * 32 + mi * 16 + quad * 4 + r;
        if (row < M)
          C[(size_t)row * N + bn + wn * 32 + ni * 16 + r16] = acc[mi][ni][r];
      }
}

// ---------------- fp32 tiled GEMM (tiny M1/M2 precompute) ----------------
__global__ __launch_bounds__(256) void gemm_abt(const float* __restrict__ A,
    const float* __restrict__ B, float* __restrict__ C, int M, int N, int K) {
  __shared__ float As[32][64];
  __shared__ float Bs[32][64];
  const int tid = threadIdx.x;
  const int bm = blockIdx.y * 64;
  const int bn = blockIdx.x * 64;
  const int tx = tid & 15;
  const int ty = tid >> 4;
  const int lr = tid & 63;
  const int lq = tid >> 6;
  float acc[4][4] = {};
  for (int k0 = 0; k0 < K; k0 += 32) {
#pragma unroll
    for (int s = 0; s < 2; ++s) {
      const int q = lq + s * 4;
      const int gm = bm + lr;
      float4 va = make_float4(0.f, 0.f, 0.f, 0.f);
      if (gm < M) va = *(const float4*)(A + (size_t)gm * K + k0 + q * 4);
      As[q * 4 + 0][lr] = va.x; As[q * 4 + 1][lr] = va.y;
      As[q * 4 + 2][lr] = va.z; As[q * 4 + 3][lr] = va.w;
      const int gn = bn + lr;
      float4 vb = *(const float4*)(B + (size_t)gn * K + k0 + q * 4);
      Bs[q * 4 + 0][lr] = vb.x; Bs[q * 4 + 1][lr] = vb.y;
      Bs[q * 4 + 2][lr] = vb.z; Bs[q * 4 + 3][lr] = vb.w;
    }
    __syncthreads();
#pragma unroll
    for (int kk = 0; kk < 32; ++kk) {
      float a[4], b[4];
#pragma unroll
      for (int i2 = 0; i2 < 4; ++i2) { a[i2] = As[kk][ty * 4 + i2]; b[i2] = Bs[kk][tx * 4 + i2]; }
#pragma unroll
      for (int i2 = 0; i2 < 4; ++i2)
#pragma unroll
        for (int j2 = 0; j2 < 4; ++j2)
          acc[i2][j2] = fmaf(a[i2], b[j2], acc[i2][j2]);
    }
    __syncthreads();
  }
#pragma unroll
  for (int i2 = 0; i2 < 4; ++i2) {
    const int gm = bm + ty * 4 + i2;
    if (gm >= M) continue;
#pragma unroll
    for (int j2 = 0; j2 < 4; ++j2)
      C[(size_t)gm * N + bn + tx * 4 + j2] = acc[i2][j2];
  }
}

// ---------------- Fused prep: all bf16 conversions + LoRA re-layouts ----------------
__global__ void prep_all(const float* __restrict__ x0, const float* __restrict__ W1,
    const float* __restrict__ W2, const float* __restrict__ res_W,
    const float* __restrict__ A1, const float* __restrict__ A2,
    const float* __restrict__ B1, const float* __restrict__ B2,
    unsigned short* __restrict__ x0b, unsigned short* __restrict__ W1b,
    unsigned short* __restrict__ W2b, unsigned short* __restrict__ resWb,
    float* __restrict__ Amat1, float* __restrict__ Amat2,
    unsigned short* __restrict__ Bmat1b, unsigned short* __restrict__ Bmat2b, int nx0) {
  int idx = blockIdx.x * 256 + threadIdx.x;
  if (idx < nx0) { x0b[idx] = f2bf(x0[idx]); return; } idx -= nx0;
  if (idx < D2 * EMB) { W1b[idx] = f2bf(W1[idx]); return; } idx -= D2 * EMB;
  if (idx < OUTD * D2) { W2b[idx] = f2bf(W2[idx]); return; } idx -= OUTD * D2;
  if (idx < OUTD * EMB) { resWb[idx] = f2bf(res_W[idx]); return; } idx -= OUTD * EMB;
  if (idx < 64 * EMB) { int d = idx % EMB, rk = idx / EMB, k = rk & 7, r = rk >> 3;
    Amat1[idx] = A1[(size_t)r * EMB * RANK + (size_t)d * RANK + k]; return; } idx -= 64 * EMB;
  if (idx < 64 * D2) { int d = idx % D2, rk = idx / D2, k = rk & 7, r = rk >> 3;
    Amat2[idx] = A2[(size_t)r * D2 * RANK + (size_t)d * RANK + k]; return; } idx -= 64 * D2;
  if (idx < 64 * EMB) { int d = idx % EMB, rk = idx / EMB, k = rk & 7, r = rk >> 3;
    Bmat1b[idx] = f2bf(B1[(size_t)r * EMB * RANK + (size_t)d * RANK + k]); return; } idx -= 64 * EMB;
  if (idx < 64 * D2) { int d = idx % D2, rk = idx / D2, k = rk & 7, r = rk >> 3;
    Bmat2b[idx] = f2bf(B2[(size_t)r * D2 * RANK + (size_t)d * RANK + k]); }
}

// ---------------- Matt folds ----------------
__global__ void fold_att(const float* __restrict__ M1, const float* __restrict__ attR1,
                         const float* __restrict__ M2, const float* __restrict__ attR2,
                         float* __restrict__ Matt1, float* __restrict__ Matt2) {
  int t = threadIdx.x;
  if (blockIdx.x == 0) {
    int h = t & 3, rk = t >> 2;
    float s = 0.f;
    for (int c = 0; c < HID; ++c)
      s = fmaf(M1[(size_t)rk * D2 + h * HID + c], attR1[h * HID + c], s);
    Matt1[rk * 4 + h] = s;
  } else if (t < 64) {
    float s = 0.f;
    for (int c = 0; c < OUTD; ++c) s = fmaf(M2[(size_t)t * OUTD + c], attR2[c], s);
    Matt2[t] = s;
  }
}

// ---------------- Convert M1/M2 -> bf16, same [rk][c] layout ----------------
__global__ void convert_Mb(const float* __restrict__ M1, const float* __restrict__ M2,
                           unsigned short* __restrict__ M1b, unsigned short* __restrict__ M2b) {
  int idx = blockIdx.x * 256 + threadIdx.x;
  if (idx < 64 * D2) M1b[idx] = f2bf(M1[idx]);
  else {
    idx -= 64 * D2;
    if (idx < 64 * OUTD) M2b[idx] = f2bf(M2[idx]);
  }
}

// ---------------- Coalesced rowdots (wave per row, shuffle reduce) ----------------
__global__ __launch_bounds__(256) void rowdot1_fast(const unsigned short* __restrict__ Z,
    const float* __restrict__ attL, const float* __restrict__ attR,
    float* __restrict__ al, float* __restrict__ ar, int Nn) {
  int wi = blockIdx.x * 4 + (threadIdx.x >> 6);
  int lane = threadIdx.x & 63;
  if (wi >= Nn * 4) return;
  int n = wi >> 2, h = wi & 3;
  const ushort2* z = (const ushort2*)(Z + (size_t)n * D2 + h * HID);
  ushort2 zv = z[lane];
  float2 L = ((const float2*)(attL + h * HID))[lane];
  float2 R = ((const float2*)(attR + h * HID))[lane];
  float z0 = bf2f(zv.x), z1 = bf2f(zv.y);
  float sl = z0 * L.x + z1 * L.y;
  float sr = z0 * R.x + z1 * R.y;
  for (int o = 32; o > 0; o >>= 1) { sl += __shfl_down(sl, o, 64); sr += __shfl_down(sr, o, 64); }
  if (lane == 0) { al[wi] = sl; ar[wi] = sr; }
}

__global__ __launch_bounds__(256) void rowdot2_fast(const unsigned short* __restrict__ Z,
    const float* __restrict__ attL, const float* __restrict__ attR,
    float* __restrict__ al, float* __restrict__ ar, int Nn) {
  int n = blockIdx.x * 4 + (threadIdx.x >> 6);
  int lane = threadIdx.x & 63;
  if (n >= Nn) return;
  const uint2* z = (const uint2*)(Z + (size_t)n * OUTD);
  uint2 zv = z[lane];
  float4 L = ((const float4*)attL)[lane];
  float4 R = ((const float4*)attR)[lane];
  float z0 = bf2f((unsigned short)(zv.x & 0xffff)), z1 = bf2f((unsigned short)(zv.x >> 16));
  float z2 = bf2f((unsigned short)(zv.y & 0xffff)), z3 = bf2f((unsigned short)(zv.y >> 16));
  float sl = z0 * L.x + z1 * L.y + z2 * L.z + z3 * L.w;
  float sr = z0 * R.x + z1 * R.y + z2 * R.z + z3 * R.w;
  for (int o = 32; o > 0; o >>= 1) { sl += __shfl_down(sl, o, 64); sr += __shfl_down(sr, o, 64); }
  if (lane == 0) { al[n] = sl; ar[n] = sr; }
}

// ---------------- CSR build ----------------
__global__ void hist_kernel(const int* __restrict__ ii, int* __restrict__ deg, int E) {
  int e = blockIdx.x * blockDim.x + threadIdx.x;
  if (e < E) atomicAdd(&deg[ii[e]], 1);
}

__global__ __launch_bounds__(1024) void exscan_kernel(const int* __restrict__ deg,
                                                      int* __restrict__ rowstart, int n) {
  __shared__ int wsum[16];
  int t = threadIdx.x;
  int lane = t & 63, wid = t >> 6;
  int carry = 0;
  for (int base = 0; base < n; base += 1024) {
    int v = (base + t < n) ? deg[base + t] : 0;
    int x = v;
#pragma unroll
    for (int o = 1; o < 64; o <<= 1) {
      int y = __shfl_up(x, o, 64);
      if (lane >= o) x += y;
    }
    if (lane == 63) wsum[wid] = x;
    __syncthreads();
    if (t == 0) {
      int s = carry;
      for (int w2 = 0; w2 < 16; ++w2) { int tmp = wsum[w2]; wsum[w2] = s; s += tmp; }
      carry = s;
    }
    __syncthreads();
    int incl = x + wsum[wid];
    if (base + t < n) rowstart[base + t] = incl - v;
    __syncthreads();
  }
  if (t == 0) rowstart[n] = carry;
}

__global__ void scatter_kernel(const int* __restrict__ ii, const int* __restrict__ rowstart,
                               int* __restrict__ cursor, int* __restrict__ slot_of, int E) {
  int e = blockIdx.x * blockDim.x + threadIdx.x;
  if (e >= E) return;
  int i = ii[e];
  int p = atomicAdd(&cursor[i], 1);
  slot_of[e] = rowstart[i] + p;
}

// ---------------- Layer-1 edge logits -> packed records at CSR slots ----------------
// rec1 (16 floats): [j, rt, ex0, ex1 | ex2, ex3, low0, low1 | low2..low5 | low6, low7, 0, 0]
__global__ void edge_alpha1(const int* __restrict__ ji, const int* __restrict__ ii,
                            const int* __restrict__ et, const int* __restrict__ slot_of,
                            const float* __restrict__ P1,
                            const float* __restrict__ al1, const float* __restrict__ ar1,
                            const float* __restrict__ relb1, const float* __restrict__ Matt1,
                            float4* __restrict__ recs1, int E) {
  int e = blockIdx.x * blockDim.x + threadIdx.x;
  if (e >= E) return;
  int j = ji[e], i = ii[e], rt = et[e];
  float low[RANK];
#pragma unroll
  for (int k = 0; k < RANK; ++k) low[k] = P1[(size_t)j * 64 + rt * RANK + k];
  float exv[HEADS];
#pragma unroll
  for (int h = 0; h < HEADS; ++h) {
    float a = al1[i * 4 + h] + ar1[j * 4 + h] + relb1[rt * 4 + h];
#pragma unroll
    for (int k = 0; k < RANK; ++k) a = fmaf(low[k], Matt1[(rt * RANK + k) * 4 + h], a);
    a = (a > 0.f) ? a : NEG_SLOPE * a;
    exv[h] = expf(a);
  }
  float4* rp = recs1 + (size_t)slot_of[e] * 4;
  rp[0] = make_float4(__int_as_float(j), __int_as_float(rt), exv[0], exv[1]);
  rp[1] = make_float4(exv[2], exv[3], low[0], low[1]);
  rp[2] = make_float4(low[2], low[3], low[4], low[5]);
  rp[3] = make_float4(low[6], low[7], 0.f, 0.f);
}

// ---------------- Layer-1 wave-per-node gather: softmax + agg + bias + ELU -> bf16 ----------------
// 4 waves/block, 1 node/wave, no __syncthreads. Lane owns 8 contiguous channels.
__global__ __launch_bounds__(256) void node_agg1(const float4* __restrict__ recs1,
    const int* __restrict__ rowstart, const unsigned short* __restrict__ z1b,
    const unsigned short* __restrict__ M1b, const float* __restrict__ bias1,
    unsigned short* __restrict__ h1out, int Nn) {
  const int wid = threadIdx.x >> 6;
  const int lane = threadIdx.x & 63;
  const int i = blockIdx.x * 4 + wid;
  if (i >= Nn) return;
  const int s0 = rowstart[i];
  const int deg = rowstart[i + 1] - s0;
  __shared__ float denS[4][32];
  const float* rf = (const float*)recs1;
  // den pass: lanes 0..31 own (r,h) = (lane>>2, lane&3)
  if (lane < 32) {
    int r = lane >> 2, h = lane & 3;
    float d = 0.f;
    for (int p = 0; p < deg; ++p) {
      size_t base = (size_t)(s0 + p) * 16;
      int rt = __float_as_int(rf[base + 1]);
      if (rt == r) d += rf[base + 2 + h];
    }
    denS[wid][lane] = d;
  }
  // wave-synchronous: same wave wrote denS, safe to read below
  const int h = lane >> 4;          // head for this lane's 8 channels
  const int c0 = lane * 8;
  float acc[8] = {};
  for (int p = 0; p < deg; ++p) {
    const float4* rp = recs1 + (size_t)(s0 + p) * 4;
    float4 r0 = rp[0];
    float4 r1 = rp[1];
    float4 r2 = rp[2];
    float4 r3 = rp[3];
    int j = __float_as_int(r0.x);
    int rt = __float_as_int(r0.y);
    float exh = (h & 2) ? ((h & 1) ? r1.y : r1.x) : ((h & 1) ? r0.w : r0.z);
    float w = exh / denS[wid][rt * 4 + h];
    float low[RANK] = {r1.z, r1.w, r2.x, r2.y, r2.z, r2.w, r3.x, r3.y};
    bf16x8 zv = *(const bf16x8*)(z1b + (size_t)j * D2 + c0);
    float v[8];
#pragma unroll
    for (int k = 0; k < 8; ++k) v[k] = bf2f((unsigned short)zv[k]);
#pragma unroll
    for (int kk = 0; kk < RANK; ++kk) {
      bf16x8 mv = *(const bf16x8*)(M1b + (size_t)(rt * 8 + kk) * D2 + c0);
#pragma unroll
      for (int k = 0; k < 8; ++k) v[k] = fmaf(low[kk], bf2f((unsigned short)mv[k]), v[k]);
    }
#pragma unroll
    for (int k = 0; k < 8; ++k) acc[k] = fmaf(w, v[k], acc[k]);
  }
  bf16x8 hv;
#pragma unroll
  for (int k = 0; k < 8; ++k) {
    float r = acc[k] + bias1[c0 + k];
    hv[k] = (short)f2bf(r > 0.f ? r : expm1f(r));
  }
  *(bf16x8*)(h1out + (size_t)i * D2 + c0) = hv;
}

// ---------------- Layer-2 edge logits -> packed records ----------------
// rec2 (12 floats): [j, rt, ex, low0 | low1..low4 | low5, low6, low7, 0]
__global__ void edge_alpha2(const int* __restrict__ ji, const int* __restrict__ ii,
                            const int* __restrict__ et, const int* __restrict__ slot_of,
                            const float* __restrict__ P2,
                            const float* __restrict__ al2, const float* __restrict__ ar2,
                            const float* __restrict__ relb2, const float* __restrict__ Matt2,
                            float4* __restrict__ recs2, int E) {
  int e = blockIdx.x * blockDim.x + threadIdx.x;
  if (e >= E) return;
  int j = ji[e], i = ii[e], rt = et[e];
  float low[RANK];
#pragma unroll
  for (int k = 0; k < RANK; ++k) low[k] = P2[(size_t)j * 64 + rt * RANK + k];
  float a = al2[i] + ar2[j] + relb2[rt];
#pragma unroll
  for (int k = 0; k < RANK; ++k) a = fmaf(low[k], Matt2[rt * RANK + k], a);
  a = (a > 0.f) ? a : NEG_SLOPE * a;
  float ex = expf(a);
  float4* rp = recs2 + (size_t)slot_of[e] * 3;
  rp[0] = make_float4(__int_as_float(j), __int_as_float(rt), ex, low[0]);
  rp[1] = make_float4(low[1], low[2], low[3], low[4]);
  rp[2] = make_float4(low[5], low[6], low[7], 0.f);
}

// ---------------- Layer-2 wave-per-node gather + residual + bias + LN -> out ----------------
// 4 waves/block, 1 node/wave. Lane owns 4 contiguous channels. LN via shuffle reduce.
__global__ __launch_bounds__(256) void node_agg2(const float4* __restrict__ recs2,
    const int* __restrict__ rowstart, const unsigned short* __restrict__ z2b,
    const unsigned short* __restrict__ M2b, const float* __restrict__ res,
    const float* __restrict__ bias2, const float* __restrict__ res_b,
    const float* __restrict__ ln_g, const float* __restrict__ ln_b,
    float* __restrict__ y, int Nn) {
  const int wid = threadIdx.x >> 6;
  const int lane = threadIdx.x & 63;
  const int i = blockIdx.x * 4 + wid;
  if (i >= Nn) return;
  const int s0 = rowstart[i];
  const int deg = rowstart[i + 1] - s0;
  __shared__ float denS[4][8];
  const float* rf = (const float*)recs2;
  if (lane < 8) {
    float d = 0.f;
    for (int p = 0; p < deg; ++p) {
      size_t base = (size_t)(s0 + p) * 12;
      int rt = __float_as_int(rf[base + 1]);
      if (rt == lane) d += rf[base + 2];
    }
    denS[wid][lane] = d;
  }
  const int c0 = lane * 4;
  float acc[4] = {};
  for (int p = 0; p < deg; ++p) {
    const float4* rp = recs2 + (size_t)(s0 + p) * 3;
    float4 r0 = rp[0];
    float4 r1 = rp[1];
    float4 r2 = rp[2];
    int j = __float_as_int(r0.x);
    int rt = __float_as_int(r0.y);
    float w = r0.z / denS[wid][rt];
    float low[RANK] = {r0.w, r1.x, r1.y, r1.z, r1.w, r2.x, r2.y, r2.z};
    uint2 zv = *(const uint2*)(z2b + (size_t)j * OUTD + c0);
    float v[4] = {bf2f((unsigned short)(zv.x & 0xffff)), bf2f((unsigned short)(zv.x >> 16)),
                  bf2f((unsigned short)(zv.y & 0xffff)), bf2f((unsigned short)(zv.y >> 16))};
#pragma unroll
    for (int kk = 0; kk < RANK; ++kk) {
      uint2 mv = *(const uint2*)(M2b + (size_t)(rt * 8 + kk) * OUTD + c0);
      float m0 = bf2f((unsigned short)(mv.x & 0xffff)), m1 = bf2f((unsigned short)(mv.x >> 16));
      float m2 = bf2f((unsigned short)(mv.y & 0xffff)), m3 = bf2f((unsigned short)(mv.y >> 16));
      v[0] = fmaf(low[kk], m0, v[0]);
      v[1] = fmaf(low[kk], m1, v[1]);
      v[2] = fmaf(low[kk], m2, v[2]);
      v[3] = fmaf(low[kk], m3, v[3]);
    }
#pragma unroll
    for (int k = 0; k < 4; ++k) acc[k] = fmaf(w, v[k], acc[k]);
  }
  float4 rsv = *(const float4*)(res + (size_t)i * OUTD + c0);
  float vv[4];
  vv[0] = acc[0] + rsv.x + bias2[c0 + 0] + res_b[c0 + 0];
  vv[1] = acc[1] + rsv.y + bias2[c0 + 1] + res_b[c0 + 1];
  vv[2] = acc[2] + rsv.z + bias2[c0 + 2] + res_b[c0 + 2];
  vv[3] = acc[3] + rsv.w + bias2[c0 + 3] + res_b[c0 + 3];
  float s = vv[0] + vv[1] + vv[2] + vv[3];
  for (int o = 32; o > 0; o >>= 1) s += __shfl_xor(s, o, 64);
  float mu = s * (1.f / OUTD);
  float q = 0.f;
#pragma unroll
  for (int k = 0; k < 4; ++k) { float d = vv[k] - mu; q += d * d; }
  for (int o = 32; o > 0; o >>= 1) q += __shfl_xor(q, o, 64);
  float rstd = rsqrtf(q * (1.f / OUTD) + LN_EPS);
  float4 ov;
  ov.x = (vv[0] - mu) * rstd * ln_g[c0 + 0] + ln_b[c0 + 0];
  ov.y = (vv[1] - mu) * rstd * ln_g[c0 + 1] + ln_b[c0 + 1];
  ov.z = (vv[2] - mu) * rstd * ln_g[c0 + 2] + ln_b[c0 + 2];
  ov.w = (vv[3] - mu) * rstd * ln_g[c0 + 3] + ln_b[c0 + 3];
  *(float4*)(y + (size_t)i * OUTD + c0) = ov;
}

extern "C" void kernel_launch(void* const* d_in, const int* in_sizes, int n_in,
                              void* d_out, int out_size, void* d_ws, size_t ws_size,
                              hipStream_t stream) {
  const float* x0     = (const float*)d_in[0];
  const float* A1     = (const float*)d_in[1];
  const float* B1     = (const float*)d_in[2];
  const float* W1     = (const float*)d_in[3];
  const float* attL1  = (const float*)d_in[4];
  const float* attR1  = (const float*)d_in[5];
  const float* relb1  = (const float*)d_in[6];
  const float* bias1  = (const float*)d_in[7];
  const float* A2     = (const float*)d_in[8];
  const float* B2     = (const float*)d_in[9];
  const float* W2     = (const float*)d_in[10];
  const float* attL2  = (const float*)d_in[11];
  const float* attR2  = (const float*)d_in[12];
  const float* relb2  = (const float*)d_in[13];
  const float* bias2  = (const float*)d_in[14];
  const float* res_W  = (const float*)d_in[15];
  const float* res_b  = (const float*)d_in[16];
  const float* ln_g   = (const float*)d_in[17];
  const float* ln_b   = (const float*)d_in[18];
  const int*   eidx   = (const int*)d_in[19];
  const int*   etype  = (const int*)d_in[20];
  float* out = (float*)d_out;

  const int Nn = in_sizes[0] / EMB;     // 30000
  const int E  = in_sizes[20];          // 150000
  const int* ji = eidx;
  const int* ii = eidx + E;

  // ---- workspace carve-up (float units; 16B alignment preserved) ----
  float* w = (float*)d_ws;
  size_t off = 0;
  float* o2    = w + off; off += (size_t)Nn * OUTD;
  float* P1    = w + off; off += (size_t)Nn * 64;
  float* P2    = w + off; off += (size_t)Nn * 64;
  float* M1    = w + off; off += 64 * D2;
  float* M2    = w + off; off += 64 * OUTD;
  float* Amat1 = w + off; off += 64 * EMB;
  float* Amat2 = w + off; off += 64 * D2;
  float* Matt1 = w + off; off += 64 * 4;
  float* Matt2 = w + off; off += 64;
  float* al1   = w + off; off += (size_t)Nn * 4;
  float* ar1   = w + off; off += (size_t)Nn * 4;
  float* al2   = w + off; off += (size_t)Nn;
  float* ar2   = w + off; off += (size_t)Nn;
  float4* recs1 = (float4*)(w + off); off += (size_t)E * 16;
  float4* recs2 = (float4*)(w + off); off += (size_t)E * 12;
  unsigned short* z1b    = (unsigned short*)(w + off); off += (size_t)Nn * D2 / 2;
  unsigned short* z2b    = (unsigned short*)(w + off); off += (size_t)Nn * OUTD / 2;
  unsigned short* x0b    = (unsigned short*)(w + off); off += (size_t)Nn * EMB / 2;
  unsigned short* h1b    = (unsigned short*)(w + off); off += (size_t)Nn * D2 / 2;
  unsigned short* W1b    = (unsigned short*)(w + off); off += (size_t)D2 * EMB / 2;
  unsigned short* W2b    = (unsigned short*)(w + off); off += (size_t)OUTD * D2 / 2;
  unsigned short* resWb  = (unsigned short*)(w + off); off += (size_t)OUTD * EMB / 2;
  unsigned short* Bmat1b = (unsigned short*)(w + off); off += (size_t)64 * EMB / 2;
  unsigned short* Bmat2b = (unsigned short*)(w + off); off += (size_t)64 * D2 / 2;
  unsigned short* M1b    = (unsigned short*)(w + off); off += (size_t)64 * D2 / 2;
  unsigned short* M2b    = (unsigned short*)(w + off); off += (size_t)64 * OUTD / 2;
  int* ideg     = (int*)(w + off); off += (size_t)Nn;
  int* cursor   = (int*)(w + off); off += (size_t)Nn;
  int* slot_of  = (int*)(w + off); off += (size_t)E;
  int* rowstart = (int*)(w + off); off += (size_t)Nn + 1;
  (void)ws_size; (void)n_in; (void)out_size;

  const int MT64 = (Nn + 63) / 64;
  const int MT128 = (Nn + 127) / 128;

  // 0) CSR build
  (void)hipMemsetAsync(ideg, 0, (size_t)Nn * sizeof(int), stream);
  (void)hipMemsetAsync(cursor, 0, (size_t)Nn * sizeof(int), stream);
  hist_kernel<<<(E + 255) / 256, 256, 0, stream>>>(ii, ideg, E);
  exscan_kernel<<<1, 1024, 0, stream>>>(ideg, rowstart, Nn);
  scatter_kernel<<<(E + 255) / 256, 256, 0, stream>>>(ii, rowstart, cursor, slot_of, E);

  // 1) fused conversions + LoRA re-layouts
  {
    int nx0 = Nn * EMB;
    int total = nx0 + D2 * EMB + OUTD * D2 + OUTD * EMB + 64 * EMB + 64 * D2 + 64 * EMB + 64 * D2;
    prep_all<<<(total + 255) / 256, 256, 0, stream>>>(x0, W1, W2, res_W, A1, A2, B1, B2,
        x0b, W1b, W2b, resWb, Amat1, Amat2, Bmat1b, Bmat2b, nx0);
  }

  // 2) M1/M2 + Matt folds + bf16 copies
  gemm_abt<<<dim3(D2 / 64, 1), 256, 0, stream>>>(Amat1, W1, M1, 64, D2, EMB);
  gemm_abt<<<dim3(OUTD / 64, 1), 256, 0, stream>>>(Amat2, W2, M2, 64, OUTD, D2);
  fold_att<<<2, 256, 0, stream>>>(M1, attR1, M2, attR2, Matt1, Matt2);
  convert_Mb<<<(64 * D2 + 64 * OUTD + 255) / 256, 256, 0, stream>>>(M1, M2, M1b, M2b);

  // 3) Layer-1 node GEMMs
  gemm_big_h<<<dim3(MT128, D2 / 128), 256, 0, stream>>>(x0b, W1b, z1b, Nn, D2, EMB);
  gemm_bf16t<<<dim3(MT64, 1), 256, 0, stream>>>(x0b, Bmat1b, P1, Nn, 64, EMB);

  // 4) attention dots
  rowdot1_fast<<<Nn, 256, 0, stream>>>(z1b, attL1, attR1, al1, ar1, Nn);

  // 5) Layer-1 edge logits -> records; wave-per-node gather
  edge_alpha1<<<(E + 255) / 256, 256, 0, stream>>>(ji, ii, etype, slot_of, P1, al1, ar1,
                                                   relb1, Matt1, recs1, E);
  node_agg1<<<(Nn + 3) / 4, 256, 0, stream>>>(recs1, rowstart, z1b, M1b, bias1, h1b, Nn);

  // 6) Layer-2 node GEMMs + residual
  gemm_big_h<<<dim3(MT128, OUTD / 128), 256, 0, stream>>>(h1b, W2b, z2b, Nn, OUTD, D2);
  gemm_bf16t<<<dim3(MT64, 1), 256, 0, stream>>>(h1b, Bmat2b, P2, Nn, 64, D2);
  gemm_big<<<dim3(MT128, OUTD / 128), 256, 0, stream>>>(x0b, resWb, o2, Nn, OUTD, EMB);

  // 7) Layer-2 attention dots
  rowdot2_fast<<<(Nn + 3) / 4, 256, 0, stream>>>(z2b, attL2, attR2, al2, ar2, Nn);

  // 8) Layer-2 edge logits -> records; wave-per-node gather + residual + LN
  edge_alpha2<<<(E + 255) / 256, 256, 0, stream>>>(ji, ii, etype, slot_of, P2, al2, ar2,
                                                   relb2, Matt2, recs2, E);
  node_agg2<<<(Nn + 3) / 4, 256, 0, stream>>>(recs2, rowstart, z2b, M2b, o2, bias2, res_b,
                                              ln_g, ln_b, out, Nn);
}

// Round 10
// 486.039 us; speedup vs baseline: 1.4306x; 1.0347x over previous
//
#include <hip/hip_runtime.h>
#include <cstddef>

#define NRELS 8
#define EMB 128
#define HID 128
#define OUTD 256
#define HEADS 4
#define RANK 8
#define D2 512            // HEADS*HID, conv2 input dim
#define NEG_SLOPE 0.2f
#define LN_EPS 1e-5f

typedef short bf16x8 __attribute__((ext_vector_type(8)));   // 8 bf16 in 4 VGPRs
typedef float f32x4 __attribute__((ext_vector_type(4)));

__device__ __forceinline__ unsigned short f2bf(float f) {   // RNE
  union { float f; unsigned u; } v; v.f = f;
  unsigned u = v.u;
  return (unsigned short)((u + 0x7fffu + ((u >> 16) & 1u)) >> 16);
}
__device__ __forceinline__ float bf2f(unsigned short u) {
  union { unsigned u; float f; } v; v.u = (unsigned)u << 16; return v.f;
}

// ---------------- Big-tile bf16 MFMA GEMM, bf16 output ----------------
__global__ __launch_bounds__(256) void gemm_big_h(const unsigned short* __restrict__ A,
    const unsigned short* __restrict__ B, unsigned short* __restrict__ C, int M, int N, int K) {
  __shared__ unsigned short As[128][36];
  __shared__ unsigned short Bs[128][36];
  const int tid = threadIdx.x;
  const int wave = tid >> 6;
  const int lane = tid & 63;
  const int wm = wave & 1;
  const int wn = wave >> 1;
  const int r16 = lane & 15;
  const int quad = lane >> 4;
  const int bm = blockIdx.x * 128;
  const int bn = blockIdx.y * 128;
  const int srow = tid >> 2;
  const int scol = (tid & 3) * 8;
  int ar0 = bm + srow;      if (ar0 >= M) ar0 = M - 1;
  int ar1 = bm + 64 + srow; if (ar1 >= M) ar1 = M - 1;
  const unsigned short* Ag0 = A + (size_t)ar0 * K + scol;
  const unsigned short* Ag1 = A + (size_t)ar1 * K + scol;
  const unsigned short* Bg0 = B + (size_t)(bn + srow) * K + scol;
  const unsigned short* Bg1 = B + (size_t)(bn + 64 + srow) * K + scol;
  f32x4 acc[4][4] = {};
  for (int k0 = 0; k0 < K; k0 += 32) {
    bf16x8 a0 = *(const bf16x8*)(Ag0 + k0);
    bf16x8 a1 = *(const bf16x8*)(Ag1 + k0);
    bf16x8 b0 = *(const bf16x8*)(Bg0 + k0);
    bf16x8 b1 = *(const bf16x8*)(Bg1 + k0);
    __syncthreads();
    *(bf16x8*)(&As[srow][scol]) = a0;
    *(bf16x8*)(&As[64 + srow][scol]) = a1;
    *(bf16x8*)(&Bs[srow][scol]) = b0;
    *(bf16x8*)(&Bs[64 + srow][scol]) = b1;
    __syncthreads();
    bf16x8 af[4], bfr[4];
#pragma unroll
    for (int mi = 0; mi < 4; ++mi)
      af[mi] = *(const bf16x8*)(&As[wm * 64 + mi * 16 + r16][quad * 8]);
#pragma unroll
    for (int ni = 0; ni < 4; ++ni)
      bfr[ni] = *(const bf16x8*)(&Bs[wn * 64 + ni * 16 + r16][quad * 8]);
#pragma unroll
    for (int mi = 0; mi < 4; ++mi)
#pragma unroll
      for (int ni = 0; ni < 4; ++ni)
        acc[mi][ni] = __builtin_amdgcn_mfma_f32_16x16x32_bf16(af[mi], bfr[ni], acc[mi][ni], 0, 0, 0);
  }
#pragma unroll
  for (int mi = 0; mi < 4; ++mi)
#pragma unroll
    for (int ni = 0; ni < 4; ++ni)
#pragma unroll
      for (int r = 0; r < 4; ++r) {
        int row = bm + wm * 64 + mi * 16 + quad * 4 + r;
        if (row < M)
          C[(size_t)row * N + bn + wn * 64 + ni * 16 + r16] = f2bf(acc[mi][ni][r]);
      }
}

// ---------------- Big-tile bf16 MFMA GEMM, fp32 output (residual o2) ----------------
__global__ __launch_bounds__(256) void gemm_big(const unsigned short* __restrict__ A,
    const unsigned short* __restrict__ B, float* __restrict__ C, int M, int N, int K) {
  __shared__ unsigned short As[128][36];
  __shared__ unsigned short Bs[128][36];
  const int tid = threadIdx.x;
  const int wave = tid >> 6;
  const int lane = tid & 63;
  const int wm = wave & 1;
  const int wn = wave >> 1;
  const int r16 = lane & 15;
  const int quad = lane >> 4;
  const int bm = blockIdx.x * 128;
  const int bn = blockIdx.y * 128;
  const int srow = tid >> 2;
  const int scol = (tid & 3) * 8;
  int ar0 = bm + srow;      if (ar0 >= M) ar0 = M - 1;
  int ar1 = bm + 64 + srow; if (ar1 >= M) ar1 = M - 1;
  const unsigned short* Ag0 = A + (size_t)ar0 * K + scol;
  const unsigned short* Ag1 = A + (size_t)ar1 * K + scol;
  const unsigned short* Bg0 = B + (size_t)(bn + srow) * K + scol;
  const unsigned short* Bg1 = B + (size_t)(bn + 64 + srow) * K + scol;
  f32x4 acc[4][4] = {};
  for (int k0 = 0; k0 < K; k0 += 32) {
    bf16x8 a0 = *(const bf16x8*)(Ag0 + k0);
    bf16x8 a1 = *(const bf16x8*)(Ag1 + k0);
    bf16x8 b0 = *(const bf16x8*)(Bg0 + k0);
    bf16x8 b1 = *(const bf16x8*)(Bg1 + k0);
    __syncthreads();
    *(bf16x8*)(&As[srow][scol]) = a0;
    *(bf16x8*)(&As[64 + srow][scol]) = a1;
    *(bf16x8*)(&Bs[srow][scol]) = b0;
    *(bf16x8*)(&Bs[64 + srow][scol]) = b1;
    __syncthreads();
    bf16x8 af[4], bfr[4];
#pragma unroll
    for (int mi = 0; mi < 4; ++mi)
      af[mi] = *(const bf16x8*)(&As[wm * 64 + mi * 16 + r16][quad * 8]);
#pragma unroll
    for (int ni = 0; ni < 4; ++ni)
      bfr[ni] = *(const bf16x8*)(&Bs[wn * 64 + ni * 16 + r16][quad * 8]);
#pragma unroll
    for (int mi = 0; mi < 4; ++mi)
#pragma unroll
      for (int ni = 0; ni < 4; ++ni)
        acc[mi][ni] = __builtin_amdgcn_mfma_f32_16x16x32_bf16(af[mi], bfr[ni], acc[mi][ni], 0, 0, 0);
  }
#pragma unroll
  for (int mi = 0; mi < 4; ++mi)
#pragma unroll
    for (int ni = 0; ni < 4; ++ni)
#pragma unroll
      for (int r = 0; r < 4; ++r) {
        int row = bm + wm * 64 + mi * 16 + quad * 4 + r;
        if (row < M)
          C[(size_t)row * N + bn + wn * 64 + ni * 16 + r16] = acc[mi][ni][r];
      }
}

// ---------------- 64x64 bf16 MFMA GEMM, fp32 out (N=64 P-projections) ----------------
__global__ __launch_bounds__(256) void gemm_bf16t(const unsigned short* __restrict__ A,
    const unsigned short* __restrict__ B, float* __restrict__ C, int M, int N, int K) {
  __shared__ unsigned short As[64][40];
  __shared__ unsigned short Bs[64][40];
  const int tid = threadIdx.x;
  const int wave = tid >> 6;
  const int lane = tid & 63;
  const int wm = wave & 1;
  const int wn = wave >> 1;
  const int r16 = lane & 15;
  const int quad = lane >> 4;
  const int bm = blockIdx.x * 64;
  const int bn = blockIdx.y * 64;
  const int srow = tid >> 2;
  const int schunk = tid & 3;
  int arow = bm + srow; if (arow >= M) arow = M - 1;
  const unsigned short* Ag = A + (size_t)arow * K + schunk * 8;
  const unsigned short* Bg = B + (size_t)(bn + srow) * K + schunk * 8;
  f32x4 acc[2][2] = {};
  for (int k0 = 0; k0 < K; k0 += 32) {
    bf16x8 av = *(const bf16x8*)(Ag + k0);
    bf16x8 bv = *(const bf16x8*)(Bg + k0);
    __syncthreads();
    *(bf16x8*)(&As[srow][schunk * 8]) = av;
    *(bf16x8*)(&Bs[srow][schunk * 8]) = bv;
    __syncthreads();
    bf16x8 af0 = *(const bf16x8*)(&As[wm * 32 + r16][quad * 8]);
    bf16x8 af1 = *(const bf16x8*)(&As[wm * 32 + 16 + r16][quad * 8]);
    bf16x8 bf0 = *(const bf16x8*)(&Bs[wn * 32 + r16][quad * 8]);
    bf16x8 bf1 = *(const bf16x8*)(&Bs[wn * 32 + 16 + r16][quad * 8]);
    acc[0][0] = __builtin_amdgcn_mfma_f32_16x16x32_bf16(af0, bf0, acc[0][0], 0, 0, 0);
    acc[0][1] = __builtin_amdgcn_mfma_f32_16x16x32_bf16(af0, bf1, acc[0][1], 0, 0, 0);
    acc[1][0] = __builtin_amdgcn_mfma_f32_16x16x32_bf16(af1, bf0, acc[1][0], 0, 0, 0);
    acc[1][1] = __builtin_amdgcn_mfma_f32_16x16x32_bf16(af1, bf1, acc[1][1], 0, 0, 0);
  }
#pragma unroll
  for (int mi = 0; mi < 2; ++mi)
#pragma unroll
    for (int ni = 0; ni < 2; ++ni)
#pragma unroll
      for (int r = 0; r < 4; ++r) {
        int row = bm + wm * 32 + mi * 16 + quad * 4 + r;
        if (row < M)
          C[(size_t)row * N + bn + wn * 32 + ni * 16 + r16] = acc[mi][ni][r];
      }
}

// ---------------- fp32 tiled GEMM (tiny M1/M2 precompute) ----------------
__global__ __launch_bounds__(256) void gemm_abt(const float* __restrict__ A,
    const float* __restrict__ B, float* __restrict__ C, int M, int N, int K) {
  __shared__ float As[32][64];
  __shared__ float Bs[32][64];
  const int tid = threadIdx.x;
  const int bm = blockIdx.y * 64;
  const int bn = blockIdx.x * 64;
  const int tx = tid & 15;
  const int ty = tid >> 4;
  const int lr = tid & 63;
  const int lq = tid >> 6;
  float acc[4][4] = {};
  for (int k0 = 0; k0 < K; k0 += 32) {
#pragma unroll
    for (int s = 0; s < 2; ++s) {
      const int q = lq + s * 4;
      const int gm = bm + lr;
      float4 va = make_float4(0.f, 0.f, 0.f, 0.f);
      if (gm < M) va = *(const float4*)(A + (size_t)gm * K + k0 + q * 4);
      As[q * 4 + 0][lr] = va.x; As[q * 4 + 1][lr] = va.y;
      As[q * 4 + 2][lr] = va.z; As[q * 4 + 3][lr] = va.w;
      const int gn = bn + lr;
      float4 vb = *(const float4*)(B + (size_t)gn * K + k0 + q * 4);
      Bs[q * 4 + 0][lr] = vb.x; Bs[q * 4 + 1][lr] = vb.y;
      Bs[q * 4 + 2][lr] = vb.z; Bs[q * 4 + 3][lr] = vb.w;
    }
    __syncthreads();
#pragma unroll
    for (int kk = 0; kk < 32; ++kk) {
      float a[4], b[4];
#pragma unroll
      for (int i2 = 0; i2 < 4; ++i2) { a[i2] = As[kk][ty * 4 + i2]; b[i2] = Bs[kk][tx * 4 + i2]; }
#pragma unroll
      for (int i2 = 0; i2 < 4; ++i2)
#pragma unroll
        for (int j2 = 0; j2 < 4; ++j2)
          acc[i2][j2] = fmaf(a[i2], b[j2], acc[i2][j2]);
    }
    __syncthreads();
  }
#pragma unroll
  for (int i2 = 0; i2 < 4; ++i2) {
    const int gm = bm + ty * 4 + i2;
    if (gm >= M) continue;
#pragma unroll
    for (int j2 = 0; j2 < 4; ++j2)
      C[(size_t)gm * N + bn + tx * 4 + j2] = acc[i2][j2];
  }
}

// ---------------- Fused prep: all bf16 conversions + LoRA re-layouts ----------------
__global__ void prep_all(const float* __restrict__ x0, const float* __restrict__ W1,
    const float* __restrict__ W2, const float* __restrict__ res_W,
    const float* __restrict__ A1, const float* __restrict__ A2,
    const float* __restrict__ B1, const float* __restrict__ B2,
    unsigned short* __restrict__ x0b, unsigned short* __restrict__ W1b,
    unsigned short* __restrict__ W2b, unsigned short* __restrict__ resWb,
    float* __restrict__ Amat1, float* __restrict__ Amat2,
    unsigned short* __restrict__ Bmat1b, unsigned short* __restrict__ Bmat2b, int nx0) {
  int idx = blockIdx.x * 256 + threadIdx.x;
  if (idx < nx0) { x0b[idx] = f2bf(x0[idx]); return; } idx -= nx0;
  if (idx < D2 * EMB) { W1b[idx] = f2bf(W1[idx]); return; } idx -= D2 * EMB;
  if (idx < OUTD * D2) { W2b[idx] = f2bf(W2[idx]); return; } idx -= OUTD * D2;
  if (idx < OUTD * EMB) { resWb[idx] = f2bf(res_W[idx]); return; } idx -= OUTD * EMB;
  if (idx < 64 * EMB) { int d = idx % EMB, rk = idx / EMB, k = rk & 7, r = rk >> 3;
    Amat1[idx] = A1[(size_t)r * EMB * RANK + (size_t)d * RANK + k]; return; } idx -= 64 * EMB;
  if (idx < 64 * D2) { int d = idx % D2, rk = idx / D2, k = rk & 7, r = rk >> 3;
    Amat2[idx] = A2[(size_t)r * D2 * RANK + (size_t)d * RANK + k]; return; } idx -= 64 * D2;
  if (idx < 64 * EMB) { int d = idx % EMB, rk = idx / EMB, k = rk & 7, r = rk >> 3;
    Bmat1b[idx] = f2bf(B1[(size_t)r * EMB * RANK + (size_t)d * RANK + k]); return; } idx -= 64 * EMB;
  if (idx < 64 * D2) { int d = idx % D2, rk = idx / D2, k = rk & 7, r = rk >> 3;
    Bmat2b[idx] = f2bf(B2[(size_t)r * D2 * RANK + (size_t)d * RANK + k]); }
}

// ---------------- Matt folds ----------------
__global__ void fold_att(const float* __restrict__ M1, const float* __restrict__ attR1,
                         const float* __restrict__ M2, const float* __restrict__ attR2,
                         float* __restrict__ Matt1, float* __restrict__ Matt2) {
  int t = threadIdx.x;
  if (blockIdx.x == 0) {
    int h = t & 3, rk = t >> 2;
    float s = 0.f;
    for (int c = 0; c < HID; ++c)
      s = fmaf(M1[(size_t)rk * D2 + h * HID + c], attR1[h * HID + c], s);
    Matt1[rk * 4 + h] = s;
  } else if (t < 64) {
    float s = 0.f;
    for (int c = 0; c < OUTD; ++c) s = fmaf(M2[(size_t)t * OUTD + c], attR2[c], s);
    Matt2[t] = s;
  }
}

// ---------------- Convert M1/M2 -> bf16, same [rk][c] layout ----------------
__global__ void convert_Mb(const float* __restrict__ M1, const float* __restrict__ M2,
                           unsigned short* __restrict__ M1b, unsigned short* __restrict__ M2b) {
  int idx = blockIdx.x * 256 + threadIdx.x;
  if (idx < 64 * D2) M1b[idx] = f2bf(M1[idx]);
  else {
    idx -= 64 * D2;
    if (idx < 64 * OUTD) M2b[idx] = f2bf(M2[idx]);
  }
}

// ---------------- Coalesced rowdots (wave per row, shuffle reduce) ----------------
__global__ __launch_bounds__(256) void rowdot1_fast(const unsigned short* __restrict__ Z,
    const float* __restrict__ attL, const float* __restrict__ attR,
    float* __restrict__ al, float* __restrict__ ar, int Nn) {
  int wi = blockIdx.x * 4 + (threadIdx.x >> 6);
  int lane = threadIdx.x & 63;
  if (wi >= Nn * 4) return;
  int n = wi >> 2, h = wi & 3;
  const ushort2* z = (const ushort2*)(Z + (size_t)n * D2 + h * HID);
  ushort2 zv = z[lane];
  float2 L = ((const float2*)(attL + h * HID))[lane];
  float2 R = ((const float2*)(attR + h * HID))[lane];
  float z0 = bf2f(zv.x), z1 = bf2f(zv.y);
  float sl = z0 * L.x + z1 * L.y;
  float sr = z0 * R.x + z1 * R.y;
  for (int o = 32; o > 0; o >>= 1) { sl += __shfl_down(sl, o, 64); sr += __shfl_down(sr, o, 64); }
  if (lane == 0) { al[wi] = sl; ar[wi] = sr; }
}

__global__ __launch_bounds__(256) void rowdot2_fast(const unsigned short* __restrict__ Z,
    const float* __restrict__ attL, const float* __restrict__ attR,
    float* __restrict__ al, float* __restrict__ ar, int Nn) {
  int n = blockIdx.x * 4 + (threadIdx.x >> 6);
  int lane = threadIdx.x & 63;
  if (n >= Nn) return;
  const uint2* z = (const uint2*)(Z + (size_t)n * OUTD);
  uint2 zv = z[lane];
  float4 L = ((const float4*)attL)[lane];
  float4 R = ((const float4*)attR)[lane];
  float z0 = bf2f((unsigned short)(zv.x & 0xffff)), z1 = bf2f((unsigned short)(zv.x >> 16));
  float z2 = bf2f((unsigned short)(zv.y & 0xffff)), z3 = bf2f((unsigned short)(zv.y >> 16));
  float sl = z0 * L.x + z1 * L.y + z2 * L.z + z3 * L.w;
  float sr = z0 * R.x + z1 * R.y + z2 * R.z + z3 * R.w;
  for (int o = 32; o > 0; o >>= 1) { sl += __shfl_down(sl, o, 64); sr += __shfl_down(sr, o, 64); }
  if (lane == 0) { al[n] = sl; ar[n] = sr; }
}

// ---------------- CSR build ----------------
__global__ void hist_kernel(const int* __restrict__ ii, int* __restrict__ deg, int E) {
  int e = blockIdx.x * blockDim.x + threadIdx.x;
  if (e < E) atomicAdd(&deg[ii[e]], 1);
}

__global__ __launch_bounds__(1024) void exscan_kernel(const int* __restrict__ deg,
                                                      int* __restrict__ rowstart, int n) {
  __shared__ int wsum[16];
  int t = threadIdx.x;
  int lane = t & 63, wid = t >> 6;
  int carry = 0;
  for (int base = 0; base < n; base += 1024) {
    int v = (base + t < n) ? deg[base + t] : 0;
    int x = v;
#pragma unroll
    for (int o = 1; o < 64; o <<= 1) {
      int y = __shfl_up(x, o, 64);
      if (lane >= o) x += y;
    }
    if (lane == 63) wsum[wid] = x;
    __syncthreads();
    if (t == 0) {
      int s = carry;
      for (int w2 = 0; w2 < 16; ++w2) { int tmp = wsum[w2]; wsum[w2] = s; s += tmp; }
      carry = s;
    }
    __syncthreads();
    int incl = x + wsum[wid];
    if (base + t < n) rowstart[base + t] = incl - v;
    __syncthreads();
  }
  if (t == 0) rowstart[n] = carry;
}

__global__ void scatter_kernel(const int* __restrict__ ii, const int* __restrict__ rowstart,
                               int* __restrict__ cursor, int* __restrict__ slot_of, int E) {
  int e = blockIdx.x * blockDim.x + threadIdx.x;
  if (e >= E) return;
  int i = ii[e];
  int p = atomicAdd(&cursor[i], 1);
  slot_of[e] = rowstart[i] + p;
}

// ---------------- Layer-1 edge logits -> packed records at CSR slots ----------------
// rec1 (16 floats): [j, rt, ex0, ex1 | ex2, ex3, low0, low1 | low2..low5 | low6, low7, 0, 0]
__global__ void edge_alpha1(const int* __restrict__ ji, const int* __restrict__ ii,
                            const int* __restrict__ et, const int* __restrict__ slot_of,
                            const float* __restrict__ P1,
                            const float* __restrict__ al1, const float* __restrict__ ar1,
                            const float* __restrict__ relb1, const float* __restrict__ Matt1,
                            float4* __restrict__ recs1, int E) {
  int e = blockIdx.x * blockDim.x + threadIdx.x;
  if (e >= E) return;
  int j = ji[e], i = ii[e], rt = et[e];
  float low[RANK];
#pragma unroll
  for (int k = 0; k < RANK; ++k) low[k] = P1[(size_t)j * 64 + rt * RANK + k];
  float exv[HEADS];
#pragma unroll
  for (int h = 0; h < HEADS; ++h) {
    float a = al1[i * 4 + h] + ar1[j * 4 + h] + relb1[rt * 4 + h];
#pragma unroll
    for (int k = 0; k < RANK; ++k) a = fmaf(low[k], Matt1[(rt * RANK + k) * 4 + h], a);
    a = (a > 0.f) ? a : NEG_SLOPE * a;
    exv[h] = expf(a);
  }
  float4* rp = recs1 + (size_t)slot_of[e] * 4;
  rp[0] = make_float4(__int_as_float(j), __int_as_float(rt), exv[0], exv[1]);
  rp[1] = make_float4(exv[2], exv[3], low[0], low[1]);
  rp[2] = make_float4(low[2], low[3], low[4], low[5]);
  rp[3] = make_float4(low[6], low[7], 0.f, 0.f);
}

// ---------------- Layer-1 gather: block-per-node, 4 waves = 4 heads, 2 ch/lane ----------------
// Software-pipelined: record p+1 prefetched at loop top, z-row p+1 at loop bottom.
__global__ __launch_bounds__(256) void node_agg1(const float4* __restrict__ recs1,
    const int* __restrict__ rowstart, const unsigned short* __restrict__ z1b,
    const unsigned short* __restrict__ M1b, const float* __restrict__ bias1,
    unsigned short* __restrict__ h1out, int Nn) {
  const int wv = threadIdx.x >> 6;      // wave == head
  const int lane = threadIdx.x & 63;
  const int i = blockIdx.x;
  const int s0 = rowstart[i];
  const int deg = rowstart[i + 1] - s0;
  __shared__ float denS[4][NRELS];
  const float* rf = (const float*)recs1;
  // den pass (redundant per wave; wave-synchronous LDS, no barrier)
  if (lane < NRELS) {
    float d = 0.f;
    for (int p = 0; p < deg; ++p) {
      size_t base = (size_t)(s0 + p) * 16;
      int rt = __float_as_int(rf[base + 1]);
      if (rt == lane) d += rf[base + 2 + wv];
    }
    denS[wv][lane] = d;
  }
  const int c0 = wv * 128 + lane * 2;
  float acc0 = 0.f, acc1 = 0.f;
  float4 r0, r1, r2, r3;
  unsigned zc = 0;
  if (deg > 0) {
    const float4* rp = recs1 + (size_t)s0 * 4;
    r0 = rp[0]; r1 = rp[1]; r2 = rp[2]; r3 = rp[3];
    zc = *(const unsigned*)(z1b + (size_t)__float_as_int(r0.x) * D2 + c0);
  }
  for (int p = 0; p < deg; ++p) {
    float4 n0, n1, n2, n3;
    const bool more = (p + 1 < deg);
    if (more) {
      const float4* rp = recs1 + (size_t)(s0 + p + 1) * 4;
      n0 = rp[0]; n1 = rp[1]; n2 = rp[2]; n3 = rp[3];
    }
    int rt = __float_as_int(r0.y);
    float exh = (wv & 2) ? ((wv & 1) ? r1.y : r1.x) : ((wv & 1) ? r0.w : r0.z);
    float w = exh / denS[wv][rt];
    float low[RANK] = {r1.z, r1.w, r2.x, r2.y, r2.z, r2.w, r3.x, r3.y};
    float v0 = bf2f((unsigned short)(zc & 0xffff));
    float v1 = bf2f((unsigned short)(zc >> 16));
#pragma unroll
    for (int kk = 0; kk < RANK; ++kk) {
      unsigned mv = *(const unsigned*)(M1b + (size_t)(rt * 8 + kk) * D2 + c0);
      v0 = fmaf(low[kk], bf2f((unsigned short)(mv & 0xffff)), v0);
      v1 = fmaf(low[kk], bf2f((unsigned short)(mv >> 16)), v1);
    }
    acc0 = fmaf(w, v0, acc0);
    acc1 = fmaf(w, v1, acc1);
    if (more) {
      r0 = n0; r1 = n1; r2 = n2; r3 = n3;
      zc = *(const unsigned*)(z1b + (size_t)__float_as_int(n0.x) * D2 + c0);
    }
  }
  float e0 = acc0 + bias1[c0];
  float e1 = acc1 + bias1[c0 + 1];
  e0 = e0 > 0.f ? e0 : expm1f(e0);
  e1 = e1 > 0.f ? e1 : expm1f(e1);
  unsigned ov = (unsigned)f2bf(e0) | ((unsigned)f2bf(e1) << 16);
  *(unsigned*)(h1out + (size_t)i * D2 + c0) = ov;
}

// ---------------- Layer-2 edge logits -> packed records ----------------
// rec2 (12 floats): [j, rt, ex, low0 | low1..low4 | low5, low6, low7, 0]
__global__ void edge_alpha2(const int* __restrict__ ji, const int* __restrict__ ii,
                            const int* __restrict__ et, const int* __restrict__ slot_of,
                            const float* __restrict__ P2,
                            const float* __restrict__ al2, const float* __restrict__ ar2,
                            const float* __restrict__ relb2, const float* __restrict__ Matt2,
                            float4* __restrict__ recs2, int E) {
  int e = blockIdx.x * blockDim.x + threadIdx.x;
  if (e >= E) return;
  int j = ji[e], i = ii[e], rt = et[e];
  float low[RANK];
#pragma unroll
  for (int k = 0; k < RANK; ++k) low[k] = P2[(size_t)j * 64 + rt * RANK + k];
  float a = al2[i] + ar2[j] + relb2[rt];
#pragma unroll
  for (int k = 0; k < RANK; ++k) a = fmaf(low[k], Matt2[rt * RANK + k], a);
  a = (a > 0.f) ? a : NEG_SLOPE * a;
  float ex = expf(a);
  float4* rp = recs2 + (size_t)slot_of[e] * 3;
  rp[0] = make_float4(__int_as_float(j), __int_as_float(rt), ex, low[0]);
  rp[1] = make_float4(low[1], low[2], low[3], low[4]);
  rp[2] = make_float4(low[5], low[6], low[7], 0.f);
}

// ---------------- Layer-2 wave-per-node gather + residual + bias + LN -> out ----------------
// Software-pipelined like node_agg1. 4 waves/block, 1 node/wave, 4 ch/lane.
__global__ __launch_bounds__(256) void node_agg2(const float4* __restrict__ recs2,
    const int* __restrict__ rowstart, const unsigned short* __restrict__ z2b,
    const unsigned short* __restrict__ M2b, const float* __restrict__ res,
    const float* __restrict__ bias2, const float* __restrict__ res_b,
    const float* __restrict__ ln_g, const float* __restrict__ ln_b,
    float* __restrict__ y, int Nn) {
  const int wid = threadIdx.x >> 6;
  const int lane = threadIdx.x & 63;
  const int i = blockIdx.x * 4 + wid;
  if (i >= Nn) return;
  const int s0 = rowstart[i];
  const int deg = rowstart[i + 1] - s0;
  __shared__ float denS[4][NRELS];
  const float* rf = (const float*)recs2;
  if (lane < NRELS) {
    float d = 0.f;
    for (int p = 0; p < deg; ++p) {
      size_t base = (size_t)(s0 + p) * 12;
      int rt = __float_as_int(rf[base + 1]);
      if (rt == lane) d += rf[base + 2];
    }
    denS[wid][lane] = d;
  }
  const int c0 = lane * 4;
  float acc[4] = {};
  float4 r0, r1, r2;
  uint2 zc = make_uint2(0u, 0u);
  if (deg > 0) {
    const float4* rp = recs2 + (size_t)s0 * 3;
    r0 = rp[0]; r1 = rp[1]; r2 = rp[2];
    zc = *(const uint2*)(z2b + (size_t)__float_as_int(r0.x) * OUTD + c0);
  }
  for (int p = 0; p < deg; ++p) {
    float4 n0, n1, n2;
    const bool more = (p + 1 < deg);
    if (more) {
      const float4* rp = recs2 + (size_t)(s0 + p + 1) * 3;
      n0 = rp[0]; n1 = rp[1]; n2 = rp[2];
    }
    int rt = __float_as_int(r0.y);
    float w = r0.z / denS[wid][rt];
    float low[RANK] = {r0.w, r1.x, r1.y, r1.z, r1.w, r2.x, r2.y, r2.z};
    float v[4] = {bf2f((unsigned short)(zc.x & 0xffff)), bf2f((unsigned short)(zc.x >> 16)),
                  bf2f((unsigned short)(zc.y & 0xffff)), bf2f((unsigned short)(zc.y >> 16))};
#pragma unroll
    for (int kk = 0; kk < RANK; ++kk) {
      uint2 mv = *(const uint2*)(M2b + (size_t)(rt * 8 + kk) * OUTD + c0);
      v[0] = fmaf(low[kk], bf2f((unsigned short)(mv.x & 0xffff)), v[0]);
      v[1] = fmaf(low[kk], bf2f((unsigned short)(mv.x >> 16)), v[1]);
      v[2] = fmaf(low[kk], bf2f((unsigned short)(mv.y & 0xffff)), v[2]);
      v[3] = fmaf(low[kk], bf2f((unsigned short)(mv.y >> 16)), v[3]);
    }
#pragma unroll
    for (int k = 0; k < 4; ++k) acc[k] = fmaf(w, v[k], acc[k]);
    if (more) {
      r0 = n0; r1 = n1; r2 = n2;
      zc = *(const uint2*)(z2b + (size_t)__float_as_int(n0.x) * OUTD + c0);
    }
  }
  float4 rsv = *(const float4*)(res + (size_t)i * OUTD + c0);
  float vv[4];
  vv[0] = acc[0] + rsv.x + bias2[c0 + 0] + res_b[c0 + 0];
  vv[1] = acc[1] + rsv.y + bias2[c0 + 1] + res_b[c0 + 1];
  vv[2] = acc[2] + rsv.z + bias2[c0 + 2] + res_b[c0 + 2];
  vv[3] = acc[3] + rsv.w + bias2[c0 + 3] + res_b[c0 + 3];
  float s = vv[0] + vv[1] + vv[2] + vv[3];
  for (int o = 32; o > 0; o >>= 1) s += __shfl_xor(s, o, 64);
  float mu = s * (1.f / OUTD);
  float q = 0.f;
#pragma unroll
  for (int k = 0; k < 4; ++k) { float d = vv[k] - mu; q += d * d; }
  for (int o = 32; o > 0; o >>= 1) q += __shfl_xor(q, o, 64);
  float rstd = rsqrtf(q * (1.f / OUTD) + LN_EPS);
  float4 ov;
  ov.x = (vv[0] - mu) * rstd * ln_g[c0 + 0] + ln_b[c0 + 0];
  ov.y = (vv[1] - mu) * rstd * ln_g[c0 + 1] + ln_b[c0 + 1];
  ov.z = (vv[2] - mu) * rstd * ln_g[c0 + 2] + ln_b[c0 + 2];
  ov.w = (vv[3] - mu) * rstd * ln_g[c0 + 3] + ln_b[c0 + 3];
  *(float4*)(y + (size_t)i * OUTD + c0) = ov;
}

extern "C" void kernel_launch(void* const* d_in, const int* in_sizes, int n_in,
                              void* d_out, int out_size, void* d_ws, size_t ws_size,
                              hipStream_t stream) {
  const float* x0     = (const float*)d_in[0];
  const float* A1     = (const float*)d_in[1];
  const float* B1     = (const float*)d_in[2];
  const float* W1     = (const float*)d_in[3];
  const float* attL1  = (const float*)d_in[4];
  const float* attR1  = (const float*)d_in[5];
  const float* relb1  = (const float*)d_in[6];
  const float* bias1  = (const float*)d_in[7];
  const float* A2     = (const float*)d_in[8];
  const float* B2     = (const float*)d_in[9];
  const float* W2     = (const float*)d_in[10];
  const float* attL2  = (const float*)d_in[11];
  const float* attR2  = (const float*)d_in[12];
  const float* relb2  = (const float*)d_in[13];
  const float* bias2  = (const float*)d_in[14];
  const float* res_W  = (const float*)d_in[15];
  const float* res_b  = (const float*)d_in[16];
  const float* ln_g   = (const float*)d_in[17];
  const float* ln_b   = (const float*)d_in[18];
  const int*   eidx   = (const int*)d_in[19];
  const int*   etype  = (const int*)d_in[20];
  float* out = (float*)d_out;

  const int Nn = in_sizes[0] / EMB;     // 30000
  const int E  = in_sizes[20];          // 150000
  const int* ji = eidx;
  const int* ii = eidx + E;

  // ---- workspace carve-up (float units; 16B alignment preserved) ----
  float* w = (float*)d_ws;
  size_t off = 0;
  float* o2    = w + off; off += (size_t)Nn * OUTD;
  float* P1    = w + off; off += (size_t)Nn * 64;
  float* P2    = w + off; off += (size_t)Nn * 64;
  float* M1    = w + off; off += 64 * D2;
  float* M2    = w + off; off += 64 * OUTD;
  float* Amat1 = w + off; off += 64 * EMB;
  float* Amat2 = w + off; off += 64 * D2;
  float* Matt1 = w + off; off += 64 * 4;
  float* Matt2 = w + off; off += 64;
  float* al1   = w + off; off += (size_t)Nn * 4;
  float* ar1   = w + off; off += (size_t)Nn * 4;
  float* al2   = w + off; off += (size_t)Nn;
  float* ar2   = w + off; off += (size_t)Nn;
  float4* recs1 = (float4*)(w + off); off += (size_t)E * 16;
  float4* recs2 = (float4*)(w + off); off += (size_t)E * 12;
  unsigned short* z1b    = (unsigned short*)(w + off); off += (size_t)Nn * D2 / 2;
  unsigned short* z2b    = (unsigned short*)(w + off); off += (size_t)Nn * OUTD / 2;
  unsigned short* x0b    = (unsigned short*)(w + off); off += (size_t)Nn * EMB / 2;
  unsigned short* h1b    = (unsigned short*)(w + off); off += (size_t)Nn * D2 / 2;
  unsigned short* W1b    = (unsigned short*)(w + off); off += (size_t)D2 * EMB / 2;
  unsigned short* W2b    = (unsigned short*)(w + off); off += (size_t)OUTD * D2 / 2;
  unsigned short* resWb  = (unsigned short*)(w + off); off += (size_t)OUTD * EMB / 2;
  unsigned short* Bmat1b = (unsigned short*)(w + off); off += (size_t)64 * EMB / 2;
  unsigned short* Bmat2b = (unsigned short*)(w + off); off += (size_t)64 * D2 / 2;
  unsigned short* M1b    = (unsigned short*)(w + off); off += (size_t)64 * D2 / 2;
  unsigned short* M2b    = (unsigned short*)(w + off); off += (size_t)64 * OUTD / 2;
  int* ideg     = (int*)(w + off); off += (size_t)Nn;
  int* cursor   = (int*)(w + off); off += (size_t)Nn;
  int* slot_of  = (int*)(w + off); off += (size_t)E;
  int* rowstart = (int*)(w + off); off += (size_t)Nn + 1;
  (void)ws_size; (void)n_in; (void)out_size;

  const int MT64 = (Nn + 63) / 64;
  const int MT128 = (Nn + 127) / 128;

  // 0) CSR build
  (void)hipMemsetAsync(ideg, 0, (size_t)Nn * sizeof(int), stream);
  (void)hipMemsetAsync(cursor, 0, (size_t)Nn * sizeof(int), stream);
  hist_kernel<<<(E + 255) / 256, 256, 0, stream>>>(ii, ideg, E);
  exscan_kernel<<<1, 1024, 0, stream>>>(ideg, rowstart, Nn);
  scatter_kernel<<<(E + 255) / 256, 256, 0, stream>>>(ii, rowstart, cursor, slot_of, E);

  // 1) fused conversions + LoRA re-layouts
  {
    int nx0 = Nn * EMB;
    int total = nx0 + D2 * EMB + OUTD * D2 + OUTD * EMB + 64 * EMB + 64 * D2 + 64 * EMB + 64 * D2;
    prep_all<<<(total + 255) / 256, 256, 0, stream>>>(x0, W1, W2, res_W, A1, A2, B1, B2,
        x0b, W1b, W2b, resWb, Amat1, Amat2, Bmat1b, Bmat2b, nx0);
  }

  // 2) M1/M2 + Matt folds + bf16 copies
  gemm_abt<<<dim3(D2 / 64, 1), 256, 0, stream>>>(Amat1, W1, M1, 64, D2, EMB);
  gemm_abt<<<dim3(OUTD / 64, 1), 256, 0, stream>>>(Amat2, W2, M2, 64, OUTD, D2);
  fold_att<<<2, 256, 0, stream>>>(M1, attR1, M2, attR2, Matt1, Matt2);
  convert_Mb<<<(64 * D2 + 64 * OUTD + 255) / 256, 256, 0, stream>>>(M1, M2, M1b, M2b);

  // 3) Layer-1 node GEMMs
  gemm_big_h<<<dim3(MT128, D2 / 128), 256, 0, stream>>>(x0b, W1b, z1b, Nn, D2, EMB);
  gemm_bf16t<<<dim3(MT64, 1), 256, 0, stream>>>(x0b, Bmat1b, P1, Nn, 64, EMB);

  // 4) attention dots
  rowdot1_fast<<<Nn, 256, 0, stream>>>(z1b, attL1, attR1, al1, ar1, Nn);

  // 5) Layer-1 edge logits -> records; block-per-node gather
  edge_alpha1<<<(E + 255) / 256, 256, 0, stream>>>(ji, ii, etype, slot_of, P1, al1, ar1,
                                                   relb1, Matt1, recs1, E);
  node_agg1<<<Nn, 256, 0, stream>>>(recs1, rowstart, z1b, M1b, bias1, h1b, Nn);

  // 6) Layer-2 node GEMMs + residual
  gemm_big_h<<<dim3(MT128, OUTD / 128), 256, 0, stream>>>(h1b, W2b, z2b, Nn, OUTD, D2);
  gemm_bf16t<<<dim3(MT64, 1), 256, 0, stream>>>(h1b, Bmat2b, P2, Nn, 64, D2);
  gemm_big<<<dim3(MT128, OUTD / 128), 256, 0, stream>>>(x0b, resWb, o2, Nn, OUTD, EMB);

  // 7) Layer-2 attention dots
  rowdot2_fast<<<(Nn + 3) / 4, 256, 0, stream>>>(z2b, attL2, attR2, al2, ar2, Nn);

  // 8) Layer-2 edge logits -> records; wave-per-node gather + residual + LN
  edge_alpha2<<<(E + 255) / 256, 256, 0, stream>>>(ji, ii, etype, slot_of, P2, al2, ar2,
                                                   relb2, Matt2, recs2, E);
  node_agg2<<<(Nn + 3) / 4, 256, 0, stream>>>(recs2, rowstart, z2b, M2b, o2, bias2, res_b,
                                              ln_g, ln_b, out, Nn);
}